// Round 5
// baseline (282.082 us; speedup 1.0000x reference)
//
#include <hip/hip_runtime.h>

typedef unsigned short u16;
typedef __attribute__((ext_vector_type(8))) short short8;
typedef __attribute__((ext_vector_type(4))) float floatx4;

#define N_TOK 2048
#define DIM   2048
#define NH    32
#define NKVH  4
#define HD    64
#define KVD   256

__device__ __forceinline__ float bf2f(u16 u) {
  union { unsigned i; float f; } c; c.i = ((unsigned)u) << 16; return c.f;
}
__device__ __forceinline__ u16 f2bf(float f) {
  union { float f; unsigned i; } c; c.f = f;
  unsigned x = c.i;
  return (u16)((x + 0x7fffu + ((x >> 16) & 1u)) >> 16);
}

// async global->LDS, 16B per lane (dest = wave-uniform base + lane*16)
__device__ __forceinline__ void gload16(const u16* g, u16* l) {
#if defined(__has_builtin) && __has_builtin(__builtin_amdgcn_global_load_lds)
  __builtin_amdgcn_global_load_lds(
      (const __attribute__((address_space(1))) void*)g,
      (__attribute__((address_space(3))) void*)l, 16, 0, 0);
#else
  *(short8*)l = *(const short8*)g;
#endif
}

// ---------------------------------------------------------------------------
// Fused fp32 -> bf16 conversion of x, Wq, Wk, Wv, Wo (float4 units).
// ---------------------------------------------------------------------------
#define C_X  1048576
#define C_WQ 2097152
#define C_WK 2228224
#define C_WV 2359296
#define C_WO 3407872
__global__ __launch_bounds__(256) void cvt_all(const float* __restrict__ x,
                                               const float* __restrict__ wq,
                                               const float* __restrict__ wk,
                                               const float* __restrict__ wv,
                                               const float* __restrict__ wo,
                                               u16* __restrict__ dst) {
  int i = blockIdx.x * 256 + threadIdx.x;
  const float* src; int off;
  if      (i < C_X)  { src = x;  off = 0; }
  else if (i < C_WQ) { src = wq; off = C_X; }
  else if (i < C_WK) { src = wk; off = C_WQ; }
  else if (i < C_WV) { src = wv; off = C_WK; }
  else               { src = wo; off = C_WV; }
  float4 v = ((const float4*)src)[i - off];
  ushort4 o;
  o.x = f2bf(v.x); o.y = f2bf(v.y); o.z = f2bf(v.z); o.w = f2bf(v.w);
  ((ushort4*)dst)[i] = o;
}

// ===========================================================================
// FRAG-PACKED LAYOUTS (u16 indices; lane = q*16 + r, q=lane>>4, r=lane&15):
//  Qp: [(h*64 + sq)*4 + i*2 + c]*512 + lane*8 + j
//  Kp: [((kvh*32 + kt)*8) + t*2 + c]*512 + lane*8 + j
//  Vp: [((kvh*32 + kt)*8) + s*4 + t]*512 + lane*8 + j
// Every attention fragment load = one contiguous 1KB wave read.
// ===========================================================================
// GEMM kernels: A fragments go global->VGPR directly (no LDS), prefetched
// one K-step ahead.  B tile is staged frag-packed in LDS: frag f (16 rows)
// occupies a contiguous 1KB chunk in lane order, achieved by pre-swizzling
// the per-lane GLOBAL source address (gload_lds dest stays linear).  Reads
// are then base + lane*16B: the measured conflict-free LDS pattern.
// ===========================================================================

// ---------------------------------------------------------------------------
// Fused QKV projection GEMM, 64x128 tiles, BK=32, RoPE fused, frag-packed out.
// ---------------------------------------------------------------------------
__global__ __launch_bounds__(256) void gemm_qkv(const u16* __restrict__ A,
                                                const u16* __restrict__ Wq,
                                                const u16* __restrict__ Wk,
                                                const u16* __restrict__ Wv,
                                                const float* __restrict__ cs,
                                                const float* __restrict__ sn,
                                                u16* __restrict__ Qp,
                                                u16* __restrict__ Kp,
                                                u16* __restrict__ Vp) {
  __shared__ __align__(16) u16 Bs[2][8 * 512];   // 8 frags x 1KB, double-buf
  const int tid  = threadIdx.x;
  const int lane = tid & 63;
  const int w    = tid >> 6;
  const int r    = lane & 15, q = lane >> 4;
  const int tm = blockIdx.x & 31;
  const int tn = blockIdx.x >> 5;   // 0..19
  const int wm = w & 1, wn = w >> 1;
  const int K = DIM;

  const u16* W; int wrow0;
  if (tn < 16)      { W = Wq; wrow0 = tn * 128; }
  else if (tn < 18) { W = Wk; wrow0 = (tn - 16) * 128; }
  else              { W = Wv; wrow0 = (tn - 18) * 128; }

  // B staging: thread tid serves frag f=(tid>>6)+4i, slot lane (tid&63):
  // element = W[wrow0 + f*16 + (tid&15)][k0 + ((tid>>4)&3)*8 .. +8]
  const int sr = tid & 15, sq8 = ((tid >> 4) & 3) * 8, sf = tid >> 6;
  const u16* gb0 = W + (size_t)(wrow0 + sf * 16 + sr) * K + sq8;
  const u16* gb1 = W + (size_t)(wrow0 + (sf + 4) * 16 + sr) * K + sq8;

  // A direct: this wave's two fragments (rows wm*32 + mi*16 + r)
  const u16* ga0 = A + (size_t)(tm * 64 + wm * 32 + r) * K + q * 8;
  const u16* ga1 = ga0 + (size_t)16 * K;

  floatx4 acc[2][4];
#pragma unroll
  for (int a = 0; a < 2; ++a)
#pragma unroll
    for (int b = 0; b < 4; ++b) acc[a][b] = (floatx4){0.f, 0.f, 0.f, 0.f};

  auto stageB = [&](int b, int k0) {
    gload16(gb0 + k0, &Bs[b][tid * 8]);
    gload16(gb1 + k0, &Bs[b][2048 + tid * 8]);
  };

  short8 afc[2], afn[2];
  stageB(0, 0);
  afc[0] = *(const short8*)(ga0);
  afc[1] = *(const short8*)(ga1);
  __syncthreads();                 // vmcnt(0) drain -> buf0 + afc ready
  int cb = 0;
  for (int k0 = 0; k0 < K; k0 += 32) {
    if (k0 + 32 < K) {
      stageB(cb ^ 1, k0 + 32);
      afn[0] = *(const short8*)(ga0 + k0 + 32);
      afn[1] = *(const short8*)(ga1 + k0 + 32);
    }

    short8 bf[4];
#pragma unroll
    for (int nj = 0; nj < 4; ++nj)
      bf[nj] = *(const short8*)&Bs[cb][(wn * 4 + nj) * 512 + lane * 8];
#pragma unroll
    for (int mi = 0; mi < 2; ++mi)
#pragma unroll
      for (int nj = 0; nj < 4; ++nj)
        acc[mi][nj] = __builtin_amdgcn_mfma_f32_16x16x32_bf16(afc[mi], bf[nj], acc[mi][nj], 0, 0, 0);

    __syncthreads();               // drains next-step B stage + A prefetch
    afc[0] = afn[0]; afc[1] = afn[1];
    cb ^= 1;
  }

  if (tn < 18) {
    const int head = (tn < 16) ? (tn * 2 + wn) : ((tn - 16) * 2 + wn);
#pragma unroll
    for (int mi = 0; mi < 2; ++mi)
#pragma unroll
      for (int g = 0; g < 4; ++g) {
        int row = tm * 64 + wm * 32 + mi * 16 + 4 * q + g;   // token
        const float* crow  = cs + (size_t)row * 64;
        const float* srow2 = sn + (size_t)row * 64;
#pragma unroll
        for (int nj = 0; nj < 2; ++nj) {
          int d = nj * 16 + r;               // head-dim 0..31 (pairs with d+32)
          float x0 = acc[mi][nj][g];
          float x1 = acc[mi][nj + 2][g];
          float o0 = x0 * crow[d]      - x1 * srow2[d];
          float o1 = x1 * crow[d + 32] + x0 * srow2[d + 32];
          int qq = d >> 3, j = d & 7;
          int lslot = (qq * 16 + (row & 15)) * 8 + j;
          if (tn < 16) {
            int sq = row >> 5, ii = (row >> 4) & 1;
            size_t base = ((size_t)(head * 64 + sq) * 4 + ii * 2) * 512 + lslot;
            Qp[base]       = f2bf(o0);
            Qp[base + 512] = f2bf(o1);
          } else {
            int kt = row >> 6, t = (row >> 4) & 3;
            size_t base = ((size_t)(head * 32 + kt) * 8 + t * 2) * 512 + lslot;
            Kp[base]       = f2bf(o0);
            Kp[base + 512] = f2bf(o1);
          }
        }
      }
  } else {
#pragma unroll
    for (int mi = 0; mi < 2; ++mi)
#pragma unroll
      for (int nj = 0; nj < 4; ++nj) {
        int col  = (tn - 18) * 128 + wn * 64 + nj * 16 + r;   // dim 0..255
        int kvh  = col >> 6;
        int t    = (col & 63) >> 4;
        int rr   = col & 15;
        int row0 = tm * 64 + wm * 32 + mi * 16 + 4 * q;       // token
        int kt   = row0 >> 6;
        int wk   = row0 & 63;
        int s    = wk >> 5;
        int qq   = (wk & 31) >> 3;
        int j0   = wk & 7;
        uint2 pk;
        pk.x = (unsigned)f2bf(acc[mi][nj][0]) | ((unsigned)f2bf(acc[mi][nj][1]) << 16);
        pk.y = (unsigned)f2bf(acc[mi][nj][2]) | ((unsigned)f2bf(acc[mi][nj][3]) << 16);
        size_t idx = ((size_t)(kvh * 32 + kt) * 8 + s * 4 + t) * 512 + (qq * 16 + rr) * 8 + j0;
        *(uint2*)(Vp + idx) = pk;
      }
  }
}

// ---------------------------------------------------------------------------
// Output GEMM, 64x128 tiles, BK=32, A-direct + frag-packed B LDS, fp32 out.
// ---------------------------------------------------------------------------
__global__ __launch_bounds__(256) void gemm_out(const u16* __restrict__ A,
                                                const u16* __restrict__ W,
                                                float* __restrict__ C) {
  __shared__ __align__(16) u16 Bs[2][8 * 512];
  const int tid  = threadIdx.x;
  const int lane = tid & 63;
  const int w    = tid >> 6;
  const int r    = lane & 15, q = lane >> 4;
  const int tn = blockIdx.x & 15;
  const int tm = blockIdx.x >> 4;
  const int wm = w & 1, wn = w >> 1;
  const int K = DIM;

  const int sr = tid & 15, sq8 = ((tid >> 4) & 3) * 8, sf = tid >> 6;
  const u16* gb0 = W + (size_t)(tn * 128 + sf * 16 + sr) * K + sq8;
  const u16* gb1 = W + (size_t)(tn * 128 + (sf + 4) * 16 + sr) * K + sq8;

  const u16* ga0 = A + (size_t)(tm * 64 + wm * 32 + r) * K + q * 8;
  const u16* ga1 = ga0 + (size_t)16 * K;

  floatx4 acc[2][4];
#pragma unroll
  for (int a = 0; a < 2; ++a)
#pragma unroll
    for (int b = 0; b < 4; ++b) acc[a][b] = (floatx4){0.f, 0.f, 0.f, 0.f};

  auto stageB = [&](int b, int k0) {
    gload16(gb0 + k0, &Bs[b][tid * 8]);
    gload16(gb1 + k0, &Bs[b][2048 + tid * 8]);
  };

  short8 afc[2], afn[2];
  stageB(0, 0);
  afc[0] = *(const short8*)(ga0);
  afc[1] = *(const short8*)(ga1);
  __syncthreads();
  int cb = 0;
  for (int k0 = 0; k0 < K; k0 += 32) {
    if (k0 + 32 < K) {
      stageB(cb ^ 1, k0 + 32);
      afn[0] = *(const short8*)(ga0 + k0 + 32);
      afn[1] = *(const short8*)(ga1 + k0 + 32);
    }

    short8 bf[4];
#pragma unroll
    for (int nj = 0; nj < 4; ++nj)
      bf[nj] = *(const short8*)&Bs[cb][(wn * 4 + nj) * 512 + lane * 8];
#pragma unroll
    for (int mi = 0; mi < 2; ++mi)
#pragma unroll
      for (int nj = 0; nj < 4; ++nj)
        acc[mi][nj] = __builtin_amdgcn_mfma_f32_16x16x32_bf16(afc[mi], bf[nj], acc[mi][nj], 0, 0, 0);

    __syncthreads();
    afc[0] = afn[0]; afc[1] = afn[1];
    cb ^= 1;
  }

#pragma unroll
  for (int mi = 0; mi < 2; ++mi)
#pragma unroll
    for (int g = 0; g < 4; ++g) {
      int row = tm * 64 + wm * 32 + mi * 16 + 4 * q + g;
#pragma unroll
      for (int nj = 0; nj < 4; ++nj)
        C[(size_t)row * DIM + tn * 128 + wn * 64 + nj * 16 + r] = acc[mi][nj][g];
    }
}

// ---------------------------------------------------------------------------
// Balanced pair-scheduled MFMA flash attention.
// Block p handles q-blocks {63-p, p}: tiles(63-p)+tiles(p) == 33 for ALL p,
// so every block (and every CU, under ANY dispatcher mapping) carries equal
// work. The 2 waves split the combined 33-tile list by parity (17/16 each).
// ---------------------------------------------------------------------------
__global__ __launch_bounds__(128, 2) void attn_mfma(const u16* __restrict__ Qp,
                                                    const u16* __restrict__ Kp,
                                                    const u16* __restrict__ Vp,
                                                    u16* __restrict__ Yb) {
  __shared__ __align__(16) u16 Pl[2][32][72];
  __shared__ float OcA[32][66];   // wave1's partial for q-block A
  __shared__ float OcB[32][66];   // wave0's partial for q-block B
  __shared__ float LcA[2][64], LcB[2][64];
  const int tid  = threadIdx.x;
  const int lane = tid & 63;
  const int w    = tid >> 6;       // 0 or 1
  const int r    = lane & 15;
  const int q    = lane >> 4;
  const int p    = blockIdx.x;     // 0..31 pair index
  const int h    = blockIdx.y;
  const int kvh  = h >> 3;
  const int jA   = 63 - p;         // heavy q-block
  const int jB   = p;              // light q-block
  const int baseqA = jA * 32, baseqB = jB * 32;
  const int tA = (jA >> 1) + 1, tB = (jB >> 1) + 1;   // tile counts
  const int ktmaxA = tA - 1, ktmaxB = tB - 1;

  // Q frags: one 1KB wave read each (sq == j for 32-row q-blocks)
  short8 qfA[2][2], qfB[2][2];
#pragma unroll
  for (int i = 0; i < 2; ++i)
#pragma unroll
    for (int c = 0; c < 2; ++c) {
      qfA[i][c] = *(const short8*)(Qp + ((size_t)(h * 64 + jA) * 4 + i * 2 + c) * 512 + lane * 8);
      qfB[i][c] = *(const short8*)(Qp + ((size_t)(h * 64 + jB) * 4 + i * 2 + c) * 512 + lane * 8);
    }

  floatx4 OA[2][4], OB[2][4];
  float lsumA[2], lsumB[2];
#pragma unroll
  for (int i = 0; i < 2; ++i) {
    lsumA[i] = 0.f; lsumB[i] = 0.f;
#pragma unroll
    for (int t = 0; t < 4; ++t) {
      OA[i][t] = (floatx4){0.f, 0.f, 0.f, 0.f};
      OB[i][t] = (floatx4){0.f, 0.f, 0.f, 0.f};
    }
  }

  const u16* Kbase = Kp + (size_t)(kvh * 32) * 8 * 512;
  const u16* Vbase = Vp + (size_t)(kvh * 32) * 8 * 512;

  auto loadK = [&](int kt, short8 (&kf)[4][2]) {
    const u16* kb = Kbase + (size_t)kt * 8 * 512 + lane * 8;
#pragma unroll
    for (int t = 0; t < 4; ++t) {
      kf[t][0] = *(const short8*)(kb + (t * 2 + 0) * 512);
      kf[t][1] = *(const short8*)(kb + (t * 2 + 1) * 512);
    }
  };

  auto body = [&](int kt, int ktmax, int baseq,
                  short8 (&qf)[2][2], floatx4 (&O)[2][4], float (&lsum)[2],
                  short8 (&kc)[4][2], short8 (&kn)[4][2]) {
    // V for CURRENT tile: issued first, consumed at the bottom
    short8 vb[2][4];
    {
      const u16* vbp = Vbase + (size_t)kt * 8 * 512 + lane * 8;
#pragma unroll
      for (int s = 0; s < 2; ++s)
#pragma unroll
        for (int t = 0; t < 4; ++t)
          vb[s][t] = *(const short8*)(vbp + (s * 4 + t) * 512);
    }

    // K for this wave's next tile (kt+2), clamped, branchless
    loadK(kt + 2 <= ktmax ? kt + 2 : ktmax, kn);

    // ---- S^T = K Q^T ----
    floatx4 ST[2][4];
#pragma unroll
    for (int i = 0; i < 2; ++i)
#pragma unroll
      for (int t = 0; t < 4; ++t) ST[i][t] = (floatx4){0.f, 0.f, 0.f, 0.f};
#pragma unroll
    for (int t = 0; t < 4; ++t)
#pragma unroll
      for (int i = 0; i < 2; ++i) {
        ST[i][t] = __builtin_amdgcn_mfma_f32_16x16x32_bf16(kc[t][0], qf[i][0], ST[i][t], 0, 0, 0);
        ST[i][t] = __builtin_amdgcn_mfma_f32_16x16x32_bf16(kc[t][1], qf[i][1], ST[i][t], 0, 0, 0);
      }

    // ---- causal mask (only the last tile of this q-block can clip) ----
    if (kt == ktmax) {
#pragma unroll
      for (int i = 0; i < 2; ++i) {
        int qrow = baseq + 16 * i + r;
#pragma unroll
        for (int t = 0; t < 4; ++t) {
          int key = kt * 64 + 16 * t + 4 * q;
#pragma unroll
          for (int g = 0; g < 4; ++g)
            if (key + g > qrow) ST[i][t][g] = -1e30f;
        }
      }
    }

    // ---- p = exp(scale*s); partial row-sums; packed P -> LDS ----
#pragma unroll
    for (int i = 0; i < 2; ++i)
#pragma unroll
      for (int t = 0; t < 4; ++t) {
        float p0 = __expf(0.125f * ST[i][t][0]);
        float p1 = __expf(0.125f * ST[i][t][1]);
        float p2 = __expf(0.125f * ST[i][t][2]);
        float p3 = __expf(0.125f * ST[i][t][3]);
        lsum[i] += (p0 + p1) + (p2 + p3);
        uint2 pk;
        pk.x = (unsigned)f2bf(p0) | ((unsigned)f2bf(p1) << 16);
        pk.y = (unsigned)f2bf(p2) | ((unsigned)f2bf(p3) << 16);
        *(uint2*)&Pl[w][16 * i + r][16 * t + 4 * q] = pk;   // ds_write_b64
      }

    // ---- O += P V ----
#pragma unroll
    for (int s = 0; s < 2; ++s)
#pragma unroll
      for (int i = 0; i < 2; ++i) {
        short8 pa = *(const short8*)&Pl[w][16 * i + r][32 * s + 8 * q];
#pragma unroll
        for (int t = 0; t < 4; ++t)
          O[i][t] = __builtin_amdgcn_mfma_f32_16x16x32_bf16(pa, vb[s][t], O[i][t], 0, 0, 0);
      }
  };

  auto runloop = [&](int start, int ktmax, int baseq,
                     short8 (&qf)[2][2], floatx4 (&O)[2][4], float (&lsum)[2]) {
    if (start > ktmax) return;
    short8 kA[4][2], kB[4][2];
    loadK(start, kA);
    for (int kt = start; kt <= ktmax; kt += 4) {
      body(kt, ktmax, baseq, qf, O, lsum, kA, kB);
      if (kt + 2 <= ktmax) body(kt + 2, ktmax, baseq, qf, O, lsum, kB, kA);
    }
  };

  // Wave w takes items [w::2] of the combined list [A-tiles..., B-tiles...]
  runloop(w, ktmaxA, baseqA, qfA, OA, lsumA);
  const int sB = (w + tA) & 1;   // parity continuation into the B-tiles
  runloop(sB, ktmaxB, baseqB, qfB, OB, lsumB);

  // ---- cross-wave combine: each wave publishes its partial of the OTHER
  //      wave's output block, then finalizes its own. ----
  if (w == 1) {
#pragma unroll
    for (int i = 0; i < 2; ++i) {
#pragma unroll
      for (int t = 0; t < 4; ++t)
#pragma unroll
        for (int g = 0; g < 4; ++g)
          OcA[(i * 4 + t) * 4 + g][lane] = OA[i][t][g];
      LcA[i][lane] = lsumA[i];
    }
  } else {
#pragma unroll
    for (int i = 0; i < 2; ++i) {
#pragma unroll
      for (int t = 0; t < 4; ++t)
#pragma unroll
        for (int g = 0; g < 4; ++g)
          OcB[(i * 4 + t) * 4 + g][lane] = OB[i][t][g];
      LcB[i][lane] = lsumB[i];
    }
  }
  __syncthreads();

  auto finalize = [&](int baseq, floatx4 (&O)[2][4], float (&lsum)[2]) {
#pragma unroll
    for (int i = 0; i < 2; ++i) {
      lsum[i] += __shfl_xor(lsum[i], 16);
      lsum[i] += __shfl_xor(lsum[i], 32);   // lane(q,r) holds sum for row r
    }
#pragma unroll
    for (int i = 0; i < 2; ++i) {
      float inv[4];
#pragma unroll
      for (int g = 0; g < 4; ++g)
        inv[g] = 1.f / __shfl(lsum[i], 4 * q + g);
#pragma unroll
      for (int g = 0; g < 4; ++g) {
        u16* yp = Yb + (size_t)(baseq + 16 * i + 4 * q + g) * DIM + h * 64 + r;
        yp[0]  = f2bf(O[i][0][g] * inv[g]);
        yp[16] = f2bf(O[i][1][g] * inv[g]);
        yp[32] = f2bf(O[i][2][g] * inv[g]);
        yp[48] = f2bf(O[i][3][g] * inv[g]);
      }
    }
  };

  if (w == 0) {
#pragma unroll
    for (int i = 0; i < 2; ++i) {
#pragma unroll
      for (int t = 0; t < 4; ++t)
#pragma unroll
        for (int g = 0; g < 4; ++g)
          OA[i][t][g] += OcA[(i * 4 + t) * 4 + g][lane];
      lsumA[i] += LcA[i][lane];
    }
    finalize(baseqA, OA, lsumA);
  } else {
#pragma unroll
    for (int i = 0; i < 2; ++i) {
#pragma unroll
      for (int t = 0; t < 4; ++t)
#pragma unroll
        for (int g = 0; g < 4; ++g)
          OB[i][t][g] += OcB[(i * 4 + t) * 4 + g][lane];
      lsumB[i] += LcB[i][lane];
    }
    finalize(baseqB, OB, lsumB);
  }
}

// ---------------------------------------------------------------------------
extern "C" void kernel_launch(void* const* d_in, const int* in_sizes, int n_in,
                              void* d_out, int out_size, void* d_ws, size_t ws_size,
                              hipStream_t stream) {
  const float* x  = (const float*)d_in[0];
  const float* Wq = (const float*)d_in[1];
  const float* Wk = (const float*)d_in[2];
  const float* Wv = (const float*)d_in[3];
  const float* Wo = (const float*)d_in[4];
  const float* cs = (const float*)d_in[5];
  const float* sn = (const float*)d_in[6];

  u16* ws  = (u16*)d_ws;
  u16* xb  = ws;                            // order must match cvt_all segments
  u16* Wqb = xb  + (size_t)N_TOK * DIM;
  u16* Wkb = Wqb + (size_t)DIM * DIM;
  u16* Wvb = Wkb + (size_t)KVD * DIM;
  u16* Wob = Wvb + (size_t)KVD * DIM;
  u16* Qp  = Wob + (size_t)DIM * DIM;       // frag-packed Q (8MB)
  u16* Kp  = Qp  + (size_t)N_TOK * DIM;     // frag-packed K (1MB)
  u16* Vp  = Kp  + (size_t)N_TOK * KVD;     // frag-packed V (1MB)
  u16* Yb  = Vp  + (size_t)N_TOK * KVD;

  // fp32 -> bf16 (x + 4 weights); cos/sin consumed as fp32 by gemm_qkv
  cvt_all<<<dim3(13312), 256, 0, stream>>>(x, Wq, Wk, Wv, Wo, ws);

  // Fused QKV projection + RoPE, frag-packed outputs
  gemm_qkv<<<dim3(640), 256, 0, stream>>>(xb, Wqb, Wkb, Wvb, cs, sn, Qp, Kp, Vp);

  // Balanced pair-scheduled attention (every block = exactly 33 key-tiles)
  attn_mfma<<<dim3(32, 32), 128, 0, stream>>>(Qp, Kp, Vp, Yb);

  // Output projection (fp32 straight to d_out)
  gemm_out<<<dim3(512), 256, 0, stream>>>(Yb, Wob, (float*)d_out);
}

// Round 6
// 250.446 us; speedup vs baseline: 1.1263x; 1.1263x over previous
//
#include <hip/hip_runtime.h>

typedef unsigned short u16;
typedef __attribute__((ext_vector_type(8))) short short8;
typedef __attribute__((ext_vector_type(4))) float floatx4;

#define N_TOK 2048
#define DIM   2048
#define NH    32
#define NKVH  4
#define HD    64
#define KVD   256

__device__ __forceinline__ float bf2f(u16 u) {
  union { unsigned i; float f; } c; c.i = ((unsigned)u) << 16; return c.f;
}
__device__ __forceinline__ u16 f2bf(float f) {
  union { float f; unsigned i; } c; c.f = f;
  unsigned x = c.i;
  return (u16)((x + 0x7fffu + ((x >> 16) & 1u)) >> 16);
}

// async global->LDS, 16B per lane (dest = wave-uniform base + lane*16)
__device__ __forceinline__ void gload16(const u16* g, u16* l) {
#if defined(__has_builtin) && __has_builtin(__builtin_amdgcn_global_load_lds)
  __builtin_amdgcn_global_load_lds(
      (const __attribute__((address_space(1))) void*)g,
      (__attribute__((address_space(3))) void*)l, 16, 0, 0);
#else
  *(short8*)l = *(const short8*)g;
#endif
}

// ---------------------------------------------------------------------------
// Fused fp32 -> bf16 conversion of x, Wq, Wk, Wv, Wo (float4 units).
// ---------------------------------------------------------------------------
#define C_X  1048576
#define C_WQ 2097152
#define C_WK 2228224
#define C_WV 2359296
#define C_WO 3407872
__global__ __launch_bounds__(256) void cvt_all(const float* __restrict__ x,
                                               const float* __restrict__ wq,
                                               const float* __restrict__ wk,
                                               const float* __restrict__ wv,
                                               const float* __restrict__ wo,
                                               u16* __restrict__ dst) {
  int i = blockIdx.x * 256 + threadIdx.x;
  const float* src; int off;
  if      (i < C_X)  { src = x;  off = 0; }
  else if (i < C_WQ) { src = wq; off = C_X; }
  else if (i < C_WK) { src = wk; off = C_WQ; }
  else if (i < C_WV) { src = wv; off = C_WK; }
  else               { src = wo; off = C_WV; }
  float4 v = ((const float4*)src)[i - off];
  ushort4 o;
  o.x = f2bf(v.x); o.y = f2bf(v.y); o.z = f2bf(v.z); o.w = f2bf(v.w);
  ((ushort4*)dst)[i] = o;
}

// ===========================================================================
// FRAG-PACKED LAYOUTS (u16 indices; lane = q*16 + r, q=lane>>4, r=lane&15):
//  Qp: [(h*64 + sq)*4 + i*2 + c]*512 + lane*8 + j
//  Kp: [((kvh*32 + kt)*8) + t*2 + c]*512 + lane*8 + j
//  Vp: [((kvh*32 + kt)*8) + s*4 + t]*512 + lane*8 + j
// Every attention fragment load = one contiguous 1KB wave read.
// ===========================================================================
// GEMM kernels: A (64 rows) and B (128 rows) tiles staged FRAG-PACKED in LDS:
// frag f = 16 rows x 32 cols lives at [f*512 + lane*8] (one contiguous 1KB
// chunk in MFMA lane order), achieved by pre-swizzling the per-lane GLOBAL
// source address (gload_lds dest stays linear).  Reads are base + lane*16B:
// conflict-free (verified: SQ_LDS_BANK_CONFLICT == 0 with this layout).
//
// K-loop: 3-deep counted-vmcnt pipeline (no vmcnt(0) drain in main loop):
//   prologue: stage k=0,1,2           (9 vmem ops/thread in flight)
//   iter kt:  s_waitcnt vmcnt(6)      (oldest stage landed; m135 semantics)
//             s_barrier               (all waves' stage kt landed)
//             ds_read frags + MFMA    (compiler inserts lgkmcnt)
//             s_barrier               (all waves done reading buf kt%3)
//             stage kt+3 into buf kt%3
// Tail: vmcnt(6)/vmcnt(3)/vmcnt(0) for the last three iterations.
// ===========================================================================

// ---------------------------------------------------------------------------
// Fused QKV projection GEMM, 64x128 tiles, BK=32, RoPE fused, frag-packed out.
// ---------------------------------------------------------------------------
__global__ __launch_bounds__(256) void gemm_qkv(const u16* __restrict__ A,
                                                const u16* __restrict__ Wq,
                                                const u16* __restrict__ Wk,
                                                const u16* __restrict__ Wv,
                                                const float* __restrict__ cs,
                                                const float* __restrict__ sn,
                                                u16* __restrict__ Qp,
                                                u16* __restrict__ Kp,
                                                u16* __restrict__ Vp) {
  __shared__ __align__(16) u16 As[3][2048];   // 4 frags x 1KB per stage
  __shared__ __align__(16) u16 Bs[3][4096];   // 8 frags x 1KB per stage
  const int tid  = threadIdx.x;
  const int lane = tid & 63;
  const int w    = tid >> 6;
  const int r    = lane & 15, q = lane >> 4;
  const int tm = blockIdx.x & 31;
  const int tn = blockIdx.x >> 5;   // 0..19
  const int wm = w & 1, wn = w >> 1;
  const int K = DIM;

  const u16* W; int wrow0;
  if (tn < 16)      { W = Wq; wrow0 = tn * 128; }
  else if (tn < 18) { W = Wk; wrow0 = (tn - 16) * 128; }
  else              { W = Wv; wrow0 = (tn - 18) * 128; }

  // frag-packed staging sources: thread tid serves frag sf=tid>>6, slot tid&63
  const int sr = tid & 15, sc8 = ((tid >> 4) & 3) * 8, sf = tid >> 6;
  const u16* gaS = A + (size_t)(tm * 64 + sf * 16 + sr) * K + sc8;
  const u16* gb0 = W + (size_t)(wrow0 + sf * 16 + sr) * K + sc8;
  const u16* gb1 = W + (size_t)(wrow0 + (sf + 4) * 16 + sr) * K + sc8;

  floatx4 acc[2][4];
#pragma unroll
  for (int a = 0; a < 2; ++a)
#pragma unroll
    for (int b = 0; b < 4; ++b) acc[a][b] = (floatx4){0.f, 0.f, 0.f, 0.f};

  auto stage = [&](int b, int k0) {          // exactly 3 vmem ops per thread
    gload16(gaS + k0, &As[b][tid * 8]);
    gload16(gb0 + k0, &Bs[b][tid * 8]);
    gload16(gb1 + k0, &Bs[b][2048 + tid * 8]);
  };

  stage(0, 0);
  stage(1, 32);
  stage(2, 64);
  int cb = 0;
  for (int kt = 0; kt < 64; ++kt) {
    if (kt < 62)       asm volatile("s_waitcnt vmcnt(6)" ::: "memory");
    else if (kt == 62) asm volatile("s_waitcnt vmcnt(3)" ::: "memory");
    else               asm volatile("s_waitcnt vmcnt(0)" ::: "memory");
    __builtin_amdgcn_s_barrier();
    __builtin_amdgcn_sched_barrier(0);

    short8 af[2], bf[4];
#pragma unroll
    for (int mi = 0; mi < 2; ++mi)
      af[mi] = *(const short8*)&As[cb][(wm * 2 + mi) * 512 + lane * 8];
#pragma unroll
    for (int nj = 0; nj < 4; ++nj)
      bf[nj] = *(const short8*)&Bs[cb][(wn * 4 + nj) * 512 + lane * 8];
#pragma unroll
    for (int mi = 0; mi < 2; ++mi)
#pragma unroll
      for (int nj = 0; nj < 4; ++nj)
        acc[mi][nj] = __builtin_amdgcn_mfma_f32_16x16x32_bf16(af[mi], bf[nj], acc[mi][nj], 0, 0, 0);

    __builtin_amdgcn_sched_barrier(0);
    __builtin_amdgcn_s_barrier();            // all waves done reading buf cb
    if (kt + 3 < 64) stage(cb, (kt + 3) * 32);
    cb = (cb == 2) ? 0 : cb + 1;
  }

  if (tn < 18) {
    const int head = (tn < 16) ? (tn * 2 + wn) : ((tn - 16) * 2 + wn);
#pragma unroll
    for (int mi = 0; mi < 2; ++mi)
#pragma unroll
      for (int g = 0; g < 4; ++g) {
        int row = tm * 64 + wm * 32 + mi * 16 + 4 * q + g;   // token
        const float* crow  = cs + (size_t)row * 64;
        const float* srow2 = sn + (size_t)row * 64;
#pragma unroll
        for (int nj = 0; nj < 2; ++nj) {
          int d = nj * 16 + r;               // head-dim 0..31 (pairs with d+32)
          float x0 = acc[mi][nj][g];
          float x1 = acc[mi][nj + 2][g];
          float o0 = x0 * crow[d]      - x1 * srow2[d];
          float o1 = x1 * crow[d + 32] + x0 * srow2[d + 32];
          int qq = d >> 3, j = d & 7;
          int lslot = (qq * 16 + (row & 15)) * 8 + j;
          if (tn < 16) {
            int sq = row >> 5, ii = (row >> 4) & 1;
            size_t base = ((size_t)(head * 64 + sq) * 4 + ii * 2) * 512 + lslot;
            Qp[base]       = f2bf(o0);
            Qp[base + 512] = f2bf(o1);
          } else {
            int kt2 = row >> 6, t = (row >> 4) & 3;
            size_t base = ((size_t)(head * 32 + kt2) * 8 + t * 2) * 512 + lslot;
            Kp[base]       = f2bf(o0);
            Kp[base + 512] = f2bf(o1);
          }
        }
      }
  } else {
#pragma unroll
    for (int mi = 0; mi < 2; ++mi)
#pragma unroll
      for (int nj = 0; nj < 4; ++nj) {
        int col  = (tn - 18) * 128 + wn * 64 + nj * 16 + r;   // dim 0..255
        int kvh  = col >> 6;
        int t    = (col & 63) >> 4;
        int rr   = col & 15;
        int row0 = tm * 64 + wm * 32 + mi * 16 + 4 * q;       // token
        int kt2  = row0 >> 6;
        int wk   = row0 & 63;
        int s    = wk >> 5;
        int qq   = (wk & 31) >> 3;
        int j0   = wk & 7;
        uint2 pk;
        pk.x = (unsigned)f2bf(acc[mi][nj][0]) | ((unsigned)f2bf(acc[mi][nj][1]) << 16);
        pk.y = (unsigned)f2bf(acc[mi][nj][2]) | ((unsigned)f2bf(acc[mi][nj][3]) << 16);
        size_t idx = ((size_t)(kvh * 32 + kt2) * 8 + s * 4 + t) * 512 + (qq * 16 + rr) * 8 + j0;
        *(uint2*)(Vp + idx) = pk;
      }
  }
}

// ---------------------------------------------------------------------------
// Output GEMM, 64x128 tiles, BK=32, same 3-deep counted-vmcnt pipeline.
// ---------------------------------------------------------------------------
__global__ __launch_bounds__(256) void gemm_out(const u16* __restrict__ A,
                                                const u16* __restrict__ W,
                                                float* __restrict__ C) {
  __shared__ __align__(16) u16 As[3][2048];
  __shared__ __align__(16) u16 Bs[3][4096];
  const int tid  = threadIdx.x;
  const int lane = tid & 63;
  const int w    = tid >> 6;
  const int r    = lane & 15, q = lane >> 4;
  const int tn = blockIdx.x & 15;
  const int tm = blockIdx.x >> 4;
  const int wm = w & 1, wn = w >> 1;
  const int K = DIM;

  const int sr = tid & 15, sc8 = ((tid >> 4) & 3) * 8, sf = tid >> 6;
  const u16* gaS = A + (size_t)(tm * 64 + sf * 16 + sr) * K + sc8;
  const u16* gb0 = W + (size_t)(tn * 128 + sf * 16 + sr) * K + sc8;
  const u16* gb1 = W + (size_t)(tn * 128 + (sf + 4) * 16 + sr) * K + sc8;

  floatx4 acc[2][4];
#pragma unroll
  for (int a = 0; a < 2; ++a)
#pragma unroll
    for (int b = 0; b < 4; ++b) acc[a][b] = (floatx4){0.f, 0.f, 0.f, 0.f};

  auto stage = [&](int b, int k0) {
    gload16(gaS + k0, &As[b][tid * 8]);
    gload16(gb0 + k0, &Bs[b][tid * 8]);
    gload16(gb1 + k0, &Bs[b][2048 + tid * 8]);
  };

  stage(0, 0);
  stage(1, 32);
  stage(2, 64);
  int cb = 0;
  for (int kt = 0; kt < 64; ++kt) {
    if (kt < 62)       asm volatile("s_waitcnt vmcnt(6)" ::: "memory");
    else if (kt == 62) asm volatile("s_waitcnt vmcnt(3)" ::: "memory");
    else               asm volatile("s_waitcnt vmcnt(0)" ::: "memory");
    __builtin_amdgcn_s_barrier();
    __builtin_amdgcn_sched_barrier(0);

    short8 af[2], bf[4];
#pragma unroll
    for (int mi = 0; mi < 2; ++mi)
      af[mi] = *(const short8*)&As[cb][(wm * 2 + mi) * 512 + lane * 8];
#pragma unroll
    for (int nj = 0; nj < 4; ++nj)
      bf[nj] = *(const short8*)&Bs[cb][(wn * 4 + nj) * 512 + lane * 8];
#pragma unroll
    for (int mi = 0; mi < 2; ++mi)
#pragma unroll
      for (int nj = 0; nj < 4; ++nj)
        acc[mi][nj] = __builtin_amdgcn_mfma_f32_16x16x32_bf16(af[mi], bf[nj], acc[mi][nj], 0, 0, 0);

    __builtin_amdgcn_sched_barrier(0);
    __builtin_amdgcn_s_barrier();
    if (kt + 3 < 64) stage(cb, (kt + 3) * 32);
    cb = (cb == 2) ? 0 : cb + 1;
  }

#pragma unroll
  for (int mi = 0; mi < 2; ++mi)
#pragma unroll
    for (int g = 0; g < 4; ++g) {
      int row = tm * 64 + wm * 32 + mi * 16 + 4 * q + g;
#pragma unroll
      for (int nj = 0; nj < 4; ++nj)
        C[(size_t)row * DIM + tn * 128 + wn * 64 + nj * 16 + r] = acc[mi][nj][g];
    }
}

// ---------------------------------------------------------------------------
// Balanced pair-scheduled MFMA flash attention.
// Block p handles q-blocks {63-p, p}: tiles(63-p)+tiles(p) == 33 for ALL p,
// so every block (and every CU, under ANY dispatcher mapping) carries equal
// work. The 2 waves split the combined 33-tile list by parity (17/16 each).
// ---------------------------------------------------------------------------
__global__ __launch_bounds__(128, 2) void attn_mfma(const u16* __restrict__ Qp,
                                                    const u16* __restrict__ Kp,
                                                    const u16* __restrict__ Vp,
                                                    u16* __restrict__ Yb) {
  __shared__ __align__(16) u16 Pl[2][32][72];
  __shared__ float OcA[32][66];   // wave1's partial for q-block A
  __shared__ float OcB[32][66];   // wave0's partial for q-block B
  __shared__ float LcA[2][64], LcB[2][64];
  const int tid  = threadIdx.x;
  const int lane = tid & 63;
  const int w    = tid >> 6;       // 0 or 1
  const int r    = lane & 15;
  const int q    = lane >> 4;
  const int p    = blockIdx.x;     // 0..31 pair index
  const int h    = blockIdx.y;
  const int kvh  = h >> 3;
  const int jA   = 63 - p;         // heavy q-block
  const int jB   = p;              // light q-block
  const int baseqA = jA * 32, baseqB = jB * 32;
  const int tA = (jA >> 1) + 1, tB = (jB >> 1) + 1;   // tile counts
  const int ktmaxA = tA - 1, ktmaxB = tB - 1;

  // Q frags: one 1KB wave read each (sq == j for 32-row q-blocks)
  short8 qfA[2][2], qfB[2][2];
#pragma unroll
  for (int i = 0; i < 2; ++i)
#pragma unroll
    for (int c = 0; c < 2; ++c) {
      qfA[i][c] = *(const short8*)(Qp + ((size_t)(h * 64 + jA) * 4 + i * 2 + c) * 512 + lane * 8);
      qfB[i][c] = *(const short8*)(Qp + ((size_t)(h * 64 + jB) * 4 + i * 2 + c) * 512 + lane * 8);
    }

  floatx4 OA[2][4], OB[2][4];
  float lsumA[2], lsumB[2];
#pragma unroll
  for (int i = 0; i < 2; ++i) {
    lsumA[i] = 0.f; lsumB[i] = 0.f;
#pragma unroll
    for (int t = 0; t < 4; ++t) {
      OA[i][t] = (floatx4){0.f, 0.f, 0.f, 0.f};
      OB[i][t] = (floatx4){0.f, 0.f, 0.f, 0.f};
    }
  }

  const u16* Kbase = Kp + (size_t)(kvh * 32) * 8 * 512;
  const u16* Vbase = Vp + (size_t)(kvh * 32) * 8 * 512;

  auto loadK = [&](int kt, short8 (&kf)[4][2]) {
    const u16* kb = Kbase + (size_t)kt * 8 * 512 + lane * 8;
#pragma unroll
    for (int t = 0; t < 4; ++t) {
      kf[t][0] = *(const short8*)(kb + (t * 2 + 0) * 512);
      kf[t][1] = *(const short8*)(kb + (t * 2 + 1) * 512);
    }
  };

  auto body = [&](int kt, int ktmax, int baseq,
                  short8 (&qf)[2][2], floatx4 (&O)[2][4], float (&lsum)[2],
                  short8 (&kc)[4][2], short8 (&kn)[4][2]) {
    // V for CURRENT tile: issued first, consumed at the bottom
    short8 vb[2][4];
    {
      const u16* vbp = Vbase + (size_t)kt * 8 * 512 + lane * 8;
#pragma unroll
      for (int s = 0; s < 2; ++s)
#pragma unroll
        for (int t = 0; t < 4; ++t)
          vb[s][t] = *(const short8*)(vbp + (s * 4 + t) * 512);
    }

    // K for this wave's next tile (kt+2), clamped, branchless
    loadK(kt + 2 <= ktmax ? kt + 2 : ktmax, kn);

    // ---- S^T = K Q^T ----
    floatx4 ST[2][4];
#pragma unroll
    for (int i = 0; i < 2; ++i)
#pragma unroll
      for (int t = 0; t < 4; ++t) ST[i][t] = (floatx4){0.f, 0.f, 0.f, 0.f};
#pragma unroll
    for (int t = 0; t < 4; ++t)
#pragma unroll
      for (int i = 0; i < 2; ++i) {
        ST[i][t] = __builtin_amdgcn_mfma_f32_16x16x32_bf16(kc[t][0], qf[i][0], ST[i][t], 0, 0, 0);
        ST[i][t] = __builtin_amdgcn_mfma_f32_16x16x32_bf16(kc[t][1], qf[i][1], ST[i][t], 0, 0, 0);
      }

    // ---- causal mask (only the last tile of this q-block can clip) ----
    if (kt == ktmax) {
#pragma unroll
      for (int i = 0; i < 2; ++i) {
        int qrow = baseq + 16 * i + r;
#pragma unroll
        for (int t = 0; t < 4; ++t) {
          int key = kt * 64 + 16 * t + 4 * q;
#pragma unroll
          for (int g = 0; g < 4; ++g)
            if (key + g > qrow) ST[i][t][g] = -1e30f;
        }
      }
    }

    // ---- p = exp(scale*s); partial row-sums; packed P -> LDS ----
#pragma unroll
    for (int i = 0; i < 2; ++i)
#pragma unroll
      for (int t = 0; t < 4; ++t) {
        float p0 = __expf(0.125f * ST[i][t][0]);
        float p1 = __expf(0.125f * ST[i][t][1]);
        float p2 = __expf(0.125f * ST[i][t][2]);
        float p3 = __expf(0.125f * ST[i][t][3]);
        lsum[i] += (p0 + p1) + (p2 + p3);
        uint2 pk;
        pk.x = (unsigned)f2bf(p0) | ((unsigned)f2bf(p1) << 16);
        pk.y = (unsigned)f2bf(p2) | ((unsigned)f2bf(p3) << 16);
        *(uint2*)&Pl[w][16 * i + r][16 * t + 4 * q] = pk;   // ds_write_b64
      }

    // ---- O += P V ----
#pragma unroll
    for (int s = 0; s < 2; ++s)
#pragma unroll
      for (int i = 0; i < 2; ++i) {
        short8 pa = *(const short8*)&Pl[w][16 * i + r][32 * s + 8 * q];
#pragma unroll
        for (int t = 0; t < 4; ++t)
          O[i][t] = __builtin_amdgcn_mfma_f32_16x16x32_bf16(pa, vb[s][t], O[i][t], 0, 0, 0);
      }
  };

  auto runloop = [&](int start, int ktmax, int baseq,
                     short8 (&qf)[2][2], floatx4 (&O)[2][4], float (&lsum)[2]) {
    if (start > ktmax) return;
    short8 kA[4][2], kB[4][2];
    loadK(start, kA);
    for (int kt = start; kt <= ktmax; kt += 4) {
      body(kt, ktmax, baseq, qf, O, lsum, kA, kB);
      if (kt + 2 <= ktmax) body(kt + 2, ktmax, baseq, qf, O, lsum, kB, kA);
    }
  };

  // Wave w takes items [w::2] of the combined list [A-tiles..., B-tiles...]
  runloop(w, ktmaxA, baseqA, qfA, OA, lsumA);
  const int sB = (w + tA) & 1;   // parity continuation into the B-tiles
  runloop(sB, ktmaxB, baseqB, qfB, OB, lsumB);

  // ---- cross-wave combine: each wave publishes its partial of the OTHER
  //      wave's output block, then finalizes its own. ----
  if (w == 1) {
#pragma unroll
    for (int i = 0; i < 2; ++i) {
#pragma unroll
      for (int t = 0; t < 4; ++t)
#pragma unroll
        for (int g = 0; g < 4; ++g)
          OcA[(i * 4 + t) * 4 + g][lane] = OA[i][t][g];
      LcA[i][lane] = lsumA[i];
    }
  } else {
#pragma unroll
    for (int i = 0; i < 2; ++i) {
#pragma unroll
      for (int t = 0; t < 4; ++t)
#pragma unroll
        for (int g = 0; g < 4; ++g)
          OcB[(i * 4 + t) * 4 + g][lane] = OB[i][t][g];
      LcB[i][lane] = lsumB[i];
    }
  }
  __syncthreads();

  auto finalize = [&](int baseq, floatx4 (&O)[2][4], float (&lsum)[2]) {
#pragma unroll
    for (int i = 0; i < 2; ++i) {
      lsum[i] += __shfl_xor(lsum[i], 16);
      lsum[i] += __shfl_xor(lsum[i], 32);   // lane(q,r) holds sum for row r
    }
#pragma unroll
    for (int i = 0; i < 2; ++i) {
      float inv[4];
#pragma unroll
      for (int g = 0; g < 4; ++g)
        inv[g] = 1.f / __shfl(lsum[i], 4 * q + g);
#pragma unroll
      for (int g = 0; g < 4; ++g) {
        u16* yp = Yb + (size_t)(baseq + 16 * i + 4 * q + g) * DIM + h * 64 + r;
        yp[0]  = f2bf(O[i][0][g] * inv[g]);
        yp[16] = f2bf(O[i][1][g] * inv[g]);
        yp[32] = f2bf(O[i][2][g] * inv[g]);
        yp[48] = f2bf(O[i][3][g] * inv[g]);
      }
    }
  };

  if (w == 0) {
#pragma unroll
    for (int i = 0; i < 2; ++i) {
#pragma unroll
      for (int t = 0; t < 4; ++t)
#pragma unroll
        for (int g = 0; g < 4; ++g)
          OA[i][t][g] += OcA[(i * 4 + t) * 4 + g][lane];
      lsumA[i] += LcA[i][lane];
    }
    finalize(baseqA, OA, lsumA);
  } else {
#pragma unroll
    for (int i = 0; i < 2; ++i) {
#pragma unroll
      for (int t = 0; t < 4; ++t)
#pragma unroll
        for (int g = 0; g < 4; ++g)
          OB[i][t][g] += OcB[(i * 4 + t) * 4 + g][lane];
      lsumB[i] += LcB[i][lane];
    }
    finalize(baseqB, OB, lsumB);
  }
}

// ---------------------------------------------------------------------------
extern "C" void kernel_launch(void* const* d_in, const int* in_sizes, int n_in,
                              void* d_out, int out_size, void* d_ws, size_t ws_size,
                              hipStream_t stream) {
  const float* x  = (const float*)d_in[0];
  const float* Wq = (const float*)d_in[1];
  const float* Wk = (const float*)d_in[2];
  const float* Wv = (const float*)d_in[3];
  const float* Wo = (const float*)d_in[4];
  const float* cs = (const float*)d_in[5];
  const float* sn = (const float*)d_in[6];

  u16* ws  = (u16*)d_ws;
  u16* xb  = ws;                            // order must match cvt_all segments
  u16* Wqb = xb  + (size_t)N_TOK * DIM;
  u16* Wkb = Wqb + (size_t)DIM * DIM;
  u16* Wvb = Wkb + (size_t)KVD * DIM;
  u16* Wob = Wvb + (size_t)KVD * DIM;
  u16* Qp  = Wob + (size_t)DIM * DIM;       // frag-packed Q (8MB)
  u16* Kp  = Qp  + (size_t)N_TOK * DIM;     // frag-packed K (1MB)
  u16* Vp  = Kp  + (size_t)N_TOK * KVD;     // frag-packed V (1MB)
  u16* Yb  = Vp  + (size_t)N_TOK * KVD;

  // fp32 -> bf16 (x + 4 weights); cos/sin consumed as fp32 by gemm_qkv
  cvt_all<<<dim3(13312), 256, 0, stream>>>(x, Wq, Wk, Wv, Wo, ws);

  // Fused QKV projection + RoPE, frag-packed outputs
  gemm_qkv<<<dim3(640), 256, 0, stream>>>(xb, Wqb, Wkb, Wvb, cs, sn, Qp, Kp, Vp);

  // Balanced pair-scheduled attention (every block = exactly 33 key-tiles)
  attn_mfma<<<dim3(32, 32), 128, 0, stream>>>(Qp, Kp, Vp, Yb);

  // Output projection (fp32 straight to d_out)
  gemm_out<<<dim3(512), 256, 0, stream>>>(Yb, Wob, (float*)d_out);
}

// Round 8
// 248.365 us; speedup vs baseline: 1.1358x; 1.0084x over previous
//
#include <hip/hip_runtime.h>

typedef unsigned short u16;
typedef __attribute__((ext_vector_type(8))) short short8;
typedef __attribute__((ext_vector_type(4))) float floatx4;

#define N_TOK 2048
#define DIM   2048
#define NH    32
#define NKVH  4
#define HD    64
#define KVD   256

__device__ __forceinline__ float bf2f(u16 u) {
  union { unsigned i; float f; } c; c.i = ((unsigned)u) << 16; return c.f;
}
__device__ __forceinline__ u16 f2bf(float f) {
  union { float f; unsigned i; } c; c.f = f;
  unsigned x = c.i;
  return (u16)((x + 0x7fffu + ((x >> 16) & 1u)) >> 16);
}

// async global->LDS, 16B per lane (dest = wave-uniform base + lane*16)
__device__ __forceinline__ void gload16(const u16* g, u16* l) {
#if defined(__has_builtin) && __has_builtin(__builtin_amdgcn_global_load_lds)
  __builtin_amdgcn_global_load_lds(
      (const __attribute__((address_space(1))) void*)g,
      (__attribute__((address_space(3))) void*)l, 16, 0, 0);
#else
  *(short8*)l = *(const short8*)g;
#endif
}

// ---------------------------------------------------------------------------
// Fused fp32 -> bf16 conversion of x, Wq, Wk, Wv, Wo (float4 units).
// ---------------------------------------------------------------------------
#define C_X  1048576
#define C_WQ 2097152
#define C_WK 2228224
#define C_WV 2359296
#define C_WO 3407872
__global__ __launch_bounds__(256) void cvt_all(const float* __restrict__ x,
                                               const float* __restrict__ wq,
                                               const float* __restrict__ wk,
                                               const float* __restrict__ wv,
                                               const float* __restrict__ wo,
                                               u16* __restrict__ dst) {
  int i = blockIdx.x * 256 + threadIdx.x;
  const float* src; int off;
  if      (i < C_X)  { src = x;  off = 0; }
  else if (i < C_WQ) { src = wq; off = C_X; }
  else if (i < C_WK) { src = wk; off = C_WQ; }
  else if (i < C_WV) { src = wv; off = C_WK; }
  else               { src = wo; off = C_WV; }
  float4 v = ((const float4*)src)[i - off];
  ushort4 o;
  o.x = f2bf(v.x); o.y = f2bf(v.y); o.z = f2bf(v.z); o.w = f2bf(v.w);
  ((ushort4*)dst)[i] = o;
}

// ===========================================================================
// FRAG-PACKED LAYOUTS (u16 indices; lane = q*16 + r, q=lane>>4, r=lane&15):
//  Qp: [(h*64 + sq)*4 + i*2 + c]*512 + lane*8 + j
//  Kp: [((kvh*32 + kt)*8) + t*2 + c]*512 + lane*8 + j
//  Vp: [((kvh*32 + kt)*8) + s*4 + t]*512 + lane*8 + j
// Every attention fragment load = one contiguous 1KB wave read.
// ===========================================================================
// GEMM LDS: frag-packed chunks.  Chunk ch = f*2 + c holds the 16x32 MFMA
// operand for row-frag f, k-subtile c: lane l -> row f*16+(l&15),
// cols c*32+(l>>4)*8..+8, stored at [ch*512 + l*8].  Staged by pre-swizzling
// the per-lane GLOBAL source (gload_lds dest stays linear: base + lane*16B).
// Reads are base + lane*16B: measured conflict-free (R5/R6: BANK_CONFLICT=0).
// BK=64: 32 K-iterations, 16 MFMA per wave per iteration (2x the old ratio).
// Loop is the R3-proven form: sync; stage; sync; compute.
// ===========================================================================

// ---------------------------------------------------------------------------
// Fused QKV projection GEMM, 64x128 tiles, BK=64, RoPE fused, frag-packed out.
// Grid 640: tm = bid&31, tn = bid>>5 (0..19): 0..15 Q; 16..17 K; 18..19 V.
// ---------------------------------------------------------------------------
__global__ __launch_bounds__(256) void gemm_qkv(const u16* __restrict__ A,
                                                const u16* __restrict__ Wq,
                                                const u16* __restrict__ Wk,
                                                const u16* __restrict__ Wv,
                                                const float* __restrict__ cs,
                                                const float* __restrict__ sn,
                                                u16* __restrict__ Qp,
                                                u16* __restrict__ Kp,
                                                u16* __restrict__ Vp) {
  __shared__ __align__(16) u16 As[8 * 512];    // 4 row-frags x 2 k-subtiles
  __shared__ __align__(16) u16 Bs[16 * 512];   // 8 row-frags x 2 k-subtiles
  const int tid  = threadIdx.x;
  const int lane = tid & 63;
  const int w    = tid >> 6;
  const int r    = lane & 15, q = lane >> 4;
  const int tm = blockIdx.x & 31;
  const int tn = blockIdx.x >> 5;   // 0..19
  const int wm = w & 1, wn = w >> 1;
  const int K = DIM;

  const u16* W; int wrow0;
  if (tn < 16)      { W = Wq; wrow0 = tn * 128; }
  else if (tn < 18) { W = Wk; wrow0 = (tn - 16) * 128; }
  else              { W = Wv; wrow0 = (tn - 18) * 128; }

  // staging sources (per-thread, +k0 each iter); chunk ch -> f=ch>>1, c=ch&1
  const int chA0 = w, chA1 = w + 4;
  const u16* gaP0 = A + (size_t)(tm * 64 + (chA0 >> 1) * 16 + r) * K + (chA0 & 1) * 32 + q * 8;
  const u16* gaP1 = A + (size_t)(tm * 64 + (chA1 >> 1) * 16 + r) * K + (chA1 & 1) * 32 + q * 8;
  const u16* gbP[4];
#pragma unroll
  for (int j = 0; j < 4; ++j) {
    int ch = w + 4 * j;
    gbP[j] = W + (size_t)(wrow0 + (ch >> 1) * 16 + r) * K + (ch & 1) * 32 + q * 8;
  }

  floatx4 acc[2][4];
#pragma unroll
  for (int a = 0; a < 2; ++a)
#pragma unroll
    for (int b = 0; b < 4; ++b) acc[a][b] = (floatx4){0.f, 0.f, 0.f, 0.f};

  for (int k0 = 0; k0 < K; k0 += 64) {
    __syncthreads();
    gload16(gaP0 + k0, &As[chA0 * 512 + lane * 8]);
    gload16(gaP1 + k0, &As[chA1 * 512 + lane * 8]);
#pragma unroll
    for (int j = 0; j < 4; ++j)
      gload16(gbP[j] + k0, &Bs[(w + 4 * j) * 512 + lane * 8]);
    __syncthreads();

    short8 af[2][2], bf[4][2];
#pragma unroll
    for (int mi = 0; mi < 2; ++mi)
#pragma unroll
      for (int c = 0; c < 2; ++c)
        af[mi][c] = *(const short8*)&As[((wm * 2 + mi) * 2 + c) * 512 + lane * 8];
#pragma unroll
    for (int nj = 0; nj < 4; ++nj)
#pragma unroll
      for (int c = 0; c < 2; ++c)
        bf[nj][c] = *(const short8*)&Bs[((wn * 4 + nj) * 2 + c) * 512 + lane * 8];
#pragma unroll
    for (int c = 0; c < 2; ++c)
#pragma unroll
      for (int mi = 0; mi < 2; ++mi)
#pragma unroll
        for (int nj = 0; nj < 4; ++nj)
          acc[mi][nj] = __builtin_amdgcn_mfma_f32_16x16x32_bf16(af[mi][c], bf[nj][c], acc[mi][nj], 0, 0, 0);
  }

  if (tn < 18) {
    const int head = (tn < 16) ? (tn * 2 + wn) : ((tn - 16) * 2 + wn);
#pragma unroll
    for (int mi = 0; mi < 2; ++mi)
#pragma unroll
      for (int g = 0; g < 4; ++g) {
        int row = tm * 64 + wm * 32 + mi * 16 + 4 * q + g;   // token
        const float* crow  = cs + (size_t)row * 64;
        const float* srow2 = sn + (size_t)row * 64;
#pragma unroll
        for (int nj = 0; nj < 2; ++nj) {
          int d = nj * 16 + r;               // head-dim 0..31 (pairs with d+32)
          float x0 = acc[mi][nj][g];
          float x1 = acc[mi][nj + 2][g];
          float o0 = x0 * crow[d]      - x1 * srow2[d];
          float o1 = x1 * crow[d + 32] + x0 * srow2[d + 32];
          int qq = d >> 3, j = d & 7;
          int lslot = (qq * 16 + (row & 15)) * 8 + j;
          if (tn < 16) {
            int sq = row >> 5, ii = (row >> 4) & 1;
            size_t base = ((size_t)(head * 64 + sq) * 4 + ii * 2) * 512 + lslot;
            Qp[base]       = f2bf(o0);
            Qp[base + 512] = f2bf(o1);
          } else {
            int kt2 = row >> 6, t = (row >> 4) & 3;
            size_t base = ((size_t)(head * 32 + kt2) * 8 + t * 2) * 512 + lslot;
            Kp[base]       = f2bf(o0);
            Kp[base + 512] = f2bf(o1);
          }
        }
      }
  } else {
#pragma unroll
    for (int mi = 0; mi < 2; ++mi)
#pragma unroll
      for (int nj = 0; nj < 4; ++nj) {
        int col  = (tn - 18) * 128 + wn * 64 + nj * 16 + r;   // dim 0..255
        int kvh  = col >> 6;
        int t    = (col & 63) >> 4;
        int rr   = col & 15;
        int row0 = tm * 64 + wm * 32 + mi * 16 + 4 * q;       // token
        int kt2  = row0 >> 6;
        int wk   = row0 & 63;
        int s    = wk >> 5;
        int qq   = (wk & 31) >> 3;
        int j0   = wk & 7;
        uint2 pk;
        pk.x = (unsigned)f2bf(acc[mi][nj][0]) | ((unsigned)f2bf(acc[mi][nj][1]) << 16);
        pk.y = (unsigned)f2bf(acc[mi][nj][2]) | ((unsigned)f2bf(acc[mi][nj][3]) << 16);
        size_t idx = ((size_t)(kvh * 32 + kt2) * 8 + s * 4 + t) * 512 + (qq * 16 + rr) * 8 + j0;
        *(uint2*)(Vp + idx) = pk;
      }
  }
}

// ---------------------------------------------------------------------------
// Output GEMM, 64x128 tiles, BK=64, frag-packed LDS, fp32 out. Grid 512.
// ---------------------------------------------------------------------------
__global__ __launch_bounds__(256) void gemm_out(const u16* __restrict__ A,
                                                const u16* __restrict__ W,
                                                float* __restrict__ C) {
  __shared__ __align__(16) u16 As[8 * 512];
  __shared__ __align__(16) u16 Bs[16 * 512];
  const int tid  = threadIdx.x;
  const int lane = tid & 63;
  const int w    = tid >> 6;
  const int r    = lane & 15, q = lane >> 4;
  const int tn = blockIdx.x & 15;
  const int tm = blockIdx.x >> 4;
  const int wm = w & 1, wn = w >> 1;
  const int K = DIM;

  const int chA0 = w, chA1 = w + 4;
  const u16* gaP0 = A + (size_t)(tm * 64 + (chA0 >> 1) * 16 + r) * K + (chA0 & 1) * 32 + q * 8;
  const u16* gaP1 = A + (size_t)(tm * 64 + (chA1 >> 1) * 16 + r) * K + (chA1 & 1) * 32 + q * 8;
  const u16* gbP[4];
#pragma unroll
  for (int j = 0; j < 4; ++j) {
    int ch = w + 4 * j;
    gbP[j] = W + (size_t)(tn * 128 + (ch >> 1) * 16 + r) * K + (ch & 1) * 32 + q * 8;
  }

  floatx4 acc[2][4];
#pragma unroll
  for (int a = 0; a < 2; ++a)
#pragma unroll
    for (int b = 0; b < 4; ++b) acc[a][b] = (floatx4){0.f, 0.f, 0.f, 0.f};

  for (int k0 = 0; k0 < K; k0 += 64) {
    __syncthreads();
    gload16(gaP0 + k0, &As[chA0 * 512 + lane * 8]);
    gload16(gaP1 + k0, &As[chA1 * 512 + lane * 8]);
#pragma unroll
    for (int j = 0; j < 4; ++j)
      gload16(gbP[j] + k0, &Bs[(w + 4 * j) * 512 + lane * 8]);
    __syncthreads();

    short8 af[2][2], bf[4][2];
#pragma unroll
    for (int mi = 0; mi < 2; ++mi)
#pragma unroll
      for (int c = 0; c < 2; ++c)
        af[mi][c] = *(const short8*)&As[((wm * 2 + mi) * 2 + c) * 512 + lane * 8];
#pragma unroll
    for (int nj = 0; nj < 4; ++nj)
#pragma unroll
      for (int c = 0; c < 2; ++c)
        bf[nj][c] = *(const short8*)&Bs[((wn * 4 + nj) * 2 + c) * 512 + lane * 8];
#pragma unroll
    for (int c = 0; c < 2; ++c)
#pragma unroll
      for (int mi = 0; mi < 2; ++mi)
#pragma unroll
        for (int nj = 0; nj < 4; ++nj)
          acc[mi][nj] = __builtin_amdgcn_mfma_f32_16x16x32_bf16(af[mi][c], bf[nj][c], acc[mi][nj], 0, 0, 0);
  }

#pragma unroll
  for (int mi = 0; mi < 2; ++mi)
#pragma unroll
    for (int g = 0; g < 4; ++g) {
      int row = tm * 64 + wm * 32 + mi * 16 + 4 * q + g;
#pragma unroll
      for (int nj = 0; nj < 4; ++nj)
        C[(size_t)row * DIM + tn * 128 + wn * 64 + nj * 16 + r] = acc[mi][nj][g];
    }
}

// ---------------------------------------------------------------------------
// Balanced pair-scheduled MFMA flash attention.
// Block p handles q-blocks {63-p, p}: tiles(63-p)+tiles(p) == 33 for ALL p,
// so every block (and every CU, under ANY dispatcher mapping) carries equal
// work. The 2 waves split the combined 33-tile list by parity (17/16 each).
// ---------------------------------------------------------------------------
__global__ __launch_bounds__(128, 2) void attn_mfma(const u16* __restrict__ Qp,
                                                    const u16* __restrict__ Kp,
                                                    const u16* __restrict__ Vp,
                                                    u16* __restrict__ Yb) {
  __shared__ __align__(16) u16 Pl[2][32][72];
  __shared__ float OcA[32][66];   // wave1's partial for q-block A
  __shared__ float OcB[32][66];   // wave0's partial for q-block B
  __shared__ float LcA[2][64], LcB[2][64];
  const int tid  = threadIdx.x;
  const int lane = tid & 63;
  const int w    = tid >> 6;       // 0 or 1
  const int r    = lane & 15;
  const int q    = lane >> 4;
  const int p    = blockIdx.x;     // 0..31 pair index
  const int h    = blockIdx.y;
  const int kvh  = h >> 3;
  const int jA   = 63 - p;         // heavy q-block
  const int jB   = p;              // light q-block
  const int baseqA = jA * 32, baseqB = jB * 32;
  const int tA = (jA >> 1) + 1, tB = (jB >> 1) + 1;   // tile counts
  const int ktmaxA = tA - 1, ktmaxB = tB - 1;

  // Q frags: one 1KB wave read each (sq == j for 32-row q-blocks)
  short8 qfA[2][2], qfB[2][2];
#pragma unroll
  for (int i = 0; i < 2; ++i)
#pragma unroll
    for (int c = 0; c < 2; ++c) {
      qfA[i][c] = *(const short8*)(Qp + ((size_t)(h * 64 + jA) * 4 + i * 2 + c) * 512 + lane * 8);
      qfB[i][c] = *(const short8*)(Qp + ((size_t)(h * 64 + jB) * 4 + i * 2 + c) * 512 + lane * 8);
    }

  floatx4 OA[2][4], OB[2][4];
  float lsumA[2], lsumB[2];
#pragma unroll
  for (int i = 0; i < 2; ++i) {
    lsumA[i] = 0.f; lsumB[i] = 0.f;
#pragma unroll
    for (int t = 0; t < 4; ++t) {
      OA[i][t] = (floatx4){0.f, 0.f, 0.f, 0.f};
      OB[i][t] = (floatx4){0.f, 0.f, 0.f, 0.f};
    }
  }

  const u16* Kbase = Kp + (size_t)(kvh * 32) * 8 * 512;
  const u16* Vbase = Vp + (size_t)(kvh * 32) * 8 * 512;

  auto loadK = [&](int kt, short8 (&kf)[4][2]) {
    const u16* kb = Kbase + (size_t)kt * 8 * 512 + lane * 8;
#pragma unroll
    for (int t = 0; t < 4; ++t) {
      kf[t][0] = *(const short8*)(kb + (t * 2 + 0) * 512);
      kf[t][1] = *(const short8*)(kb + (t * 2 + 1) * 512);
    }
  };

  auto body = [&](int kt, int ktmax, int baseq,
                  short8 (&qf)[2][2], floatx4 (&O)[2][4], float (&lsum)[2],
                  short8 (&kc)[4][2], short8 (&kn)[4][2]) {
    // V for CURRENT tile: issued first, consumed at the bottom
    short8 vb[2][4];
    {
      const u16* vbp = Vbase + (size_t)kt * 8 * 512 + lane * 8;
#pragma unroll
      for (int s = 0; s < 2; ++s)
#pragma unroll
        for (int t = 0; t < 4; ++t)
          vb[s][t] = *(const short8*)(vbp + (s * 4 + t) * 512);
    }

    // K for this wave's next tile (kt+2), clamped, branchless
    loadK(kt + 2 <= ktmax ? kt + 2 : ktmax, kn);

    // ---- S^T = K Q^T ----
    floatx4 ST[2][4];
#pragma unroll
    for (int i = 0; i < 2; ++i)
#pragma unroll
      for (int t = 0; t < 4; ++t) ST[i][t] = (floatx4){0.f, 0.f, 0.f, 0.f};
#pragma unroll
    for (int t = 0; t < 4; ++t)
#pragma unroll
      for (int i = 0; i < 2; ++i) {
        ST[i][t] = __builtin_amdgcn_mfma_f32_16x16x32_bf16(kc[t][0], qf[i][0], ST[i][t], 0, 0, 0);
        ST[i][t] = __builtin_amdgcn_mfma_f32_16x16x32_bf16(kc[t][1], qf[i][1], ST[i][t], 0, 0, 0);
      }

    // ---- causal mask (only the last tile of this q-block can clip) ----
    if (kt == ktmax) {
#pragma unroll
      for (int i = 0; i < 2; ++i) {
        int qrow = baseq + 16 * i + r;
#pragma unroll
        for (int t = 0; t < 4; ++t) {
          int key = kt * 64 + 16 * t + 4 * q;
#pragma unroll
          for (int g = 0; g < 4; ++g)
            if (key + g > qrow) ST[i][t][g] = -1e30f;
        }
      }
    }

    // ---- p = exp(scale*s); partial row-sums; packed P -> LDS ----
#pragma unroll
    for (int i = 0; i < 2; ++i)
#pragma unroll
      for (int t = 0; t < 4; ++t) {
        float p0 = __expf(0.125f * ST[i][t][0]);
        float p1 = __expf(0.125f * ST[i][t][1]);
        float p2 = __expf(0.125f * ST[i][t][2]);
        float p3 = __expf(0.125f * ST[i][t][3]);
        lsum[i] += (p0 + p1) + (p2 + p3);
        uint2 pk;
        pk.x = (unsigned)f2bf(p0) | ((unsigned)f2bf(p1) << 16);
        pk.y = (unsigned)f2bf(p2) | ((unsigned)f2bf(p3) << 16);
        *(uint2*)&Pl[w][16 * i + r][16 * t + 4 * q] = pk;   // ds_write_b64
      }

    // ---- O += P V ----
#pragma unroll
    for (int s = 0; s < 2; ++s)
#pragma unroll
      for (int i = 0; i < 2; ++i) {
        short8 pa = *(const short8*)&Pl[w][16 * i + r][32 * s + 8 * q];
#pragma unroll
        for (int t = 0; t < 4; ++t)
          O[i][t] = __builtin_amdgcn_mfma_f32_16x16x32_bf16(pa, vb[s][t], O[i][t], 0, 0, 0);
      }
  };

  auto runloop = [&](int start, int ktmax, int baseq,
                     short8 (&qf)[2][2], floatx4 (&O)[2][4], float (&lsum)[2]) {
    if (start > ktmax) return;
    short8 kA[4][2], kB[4][2];
    loadK(start, kA);
    for (int kt = start; kt <= ktmax; kt += 4) {
      body(kt, ktmax, baseq, qf, O, lsum, kA, kB);
      if (kt + 2 <= ktmax) body(kt + 2, ktmax, baseq, qf, O, lsum, kB, kA);
    }
  };

  // Wave w takes items [w::2] of the combined list [A-tiles..., B-tiles...]
  runloop(w, ktmaxA, baseqA, qfA, OA, lsumA);
  const int sB = (w + tA) & 1;   // parity continuation into the B-tiles
  runloop(sB, ktmaxB, baseqB, qfB, OB, lsumB);

  // ---- cross-wave combine: each wave publishes its partial of the OTHER
  //      wave's output block, then finalizes its own. ----
  if (w == 1) {
#pragma unroll
    for (int i = 0; i < 2; ++i) {
#pragma unroll
      for (int t = 0; t < 4; ++t)
#pragma unroll
        for (int g = 0; g < 4; ++g)
          OcA[(i * 4 + t) * 4 + g][lane] = OA[i][t][g];
      LcA[i][lane] = lsumA[i];
    }
  } else {
#pragma unroll
    for (int i = 0; i < 2; ++i) {
#pragma unroll
      for (int t = 0; t < 4; ++t)
#pragma unroll
        for (int g = 0; g < 4; ++g)
          OcB[(i * 4 + t) * 4 + g][lane] = OB[i][t][g];
      LcB[i][lane] = lsumB[i];
    }
  }
  __syncthreads();

  auto finalize = [&](int baseq, floatx4 (&O)[2][4], float (&lsum)[2]) {
#pragma unroll
    for (int i = 0; i < 2; ++i) {
      lsum[i] += __shfl_xor(lsum[i], 16);
      lsum[i] += __shfl_xor(lsum[i], 32);   // lane(q,r) holds sum for row r
    }
#pragma unroll
    for (int i = 0; i < 2; ++i) {
      float inv[4];
#pragma unroll
      for (int g = 0; g < 4; ++g)
        inv[g] = 1.f / __shfl(lsum[i], 4 * q + g);
#pragma unroll
      for (int g = 0; g < 4; ++g) {
        u16* yp = Yb + (size_t)(baseq + 16 * i + 4 * q + g) * DIM + h * 64 + r;
        yp[0]  = f2bf(O[i][0][g] * inv[g]);
        yp[16] = f2bf(O[i][1][g] * inv[g]);
        yp[32] = f2bf(O[i][2][g] * inv[g]);
        yp[48] = f2bf(O[i][3][g] * inv[g]);
      }
    }
  };

  if (w == 0) {
#pragma unroll
    for (int i = 0; i < 2; ++i) {
#pragma unroll
      for (int t = 0; t < 4; ++t)
#pragma unroll
        for (int g = 0; g < 4; ++g)
          OA[i][t][g] += OcA[(i * 4 + t) * 4 + g][lane];
      lsumA[i] += LcA[i][lane];
    }
    finalize(baseqA, OA, lsumA);
  } else {
#pragma unroll
    for (int i = 0; i < 2; ++i) {
#pragma unroll
      for (int t = 0; t < 4; ++t)
#pragma unroll
        for (int g = 0; g < 4; ++g)
          OB[i][t][g] += OcB[(i * 4 + t) * 4 + g][lane];
      lsumB[i] += LcB[i][lane];
    }
    finalize(baseqB, OB, lsumB);
  }
}

// ---------------------------------------------------------------------------
extern "C" void kernel_launch(void* const* d_in, const int* in_sizes, int n_in,
                              void* d_out, int out_size, void* d_ws, size_t ws_size,
                              hipStream_t stream) {
  const float* x  = (const float*)d_in[0];
  const float* Wq = (const float*)d_in[1];
  const float* Wk = (const float*)d_in[2];
  const float* Wv = (const float*)d_in[3];
  const float* Wo = (const float*)d_in[4];
  const float* cs = (const float*)d_in[5];
  const float* sn = (const float*)d_in[6];

  u16* ws  = (u16*)d_ws;
  u16* xb  = ws;                            // order must match cvt_all segments
  u16* Wqb = xb  + (size_t)N_TOK * DIM;
  u16* Wkb = Wqb + (size_t)DIM * DIM;
  u16* Wvb = Wkb + (size_t)KVD * DIM;
  u16* Wob = Wvb + (size_t)KVD * DIM;
  u16* Qp  = Wob + (size_t)DIM * DIM;       // frag-packed Q (8MB)
  u16* Kp  = Qp  + (size_t)N_TOK * DIM;     // frag-packed K (1MB)
  u16* Vp  = Kp  + (size_t)N_TOK * KVD;     // frag-packed V (1MB)
  u16* Yb  = Vp  + (size_t)N_TOK * KVD;

  // fp32 -> bf16 (x + 4 weights); cos/sin consumed as fp32 by gemm_qkv
  cvt_all<<<dim3(13312), 256, 0, stream>>>(x, Wq, Wk, Wv, Wo, ws);

  // Fused QKV projection + RoPE, frag-packed outputs
  gemm_qkv<<<dim3(640), 256, 0, stream>>>(xb, Wqb, Wkb, Wvb, cs, sn, Qp, Kp, Vp);

  // Balanced pair-scheduled attention (every block = exactly 33 key-tiles)
  attn_mfma<<<dim3(32, 32), 128, 0, stream>>>(Qp, Kp, Vp, Yb);

  // Output projection (fp32 straight to d_out)
  gemm_out<<<dim3(512), 256, 0, stream>>>(Yb, Wob, (float*)d_out);
}

// Round 9
// 192.066 us; speedup vs baseline: 1.4687x; 1.2931x over previous
//
#include <hip/hip_runtime.h>

typedef unsigned short u16;
typedef __attribute__((ext_vector_type(8))) short short8;
typedef __attribute__((ext_vector_type(4))) float floatx4;

#define N_TOK 2048
#define DIM   2048
#define NH    32
#define NKVH  4
#define HD    64
#define KVD   256

// packed-region offsets in the u16 workspace
#define OFF_X   0
#define OFF_WQ  4194304
#define OFF_WK  8388608
#define OFF_WV  8912896
#define OFF_WO  9437184
#define OFF_QP  13631488
#define OFF_KP  17825792
#define OFF_VP  18350080
#define OFF_YB  18874368

__device__ __forceinline__ float bf2f(u16 u) {
  union { unsigned i; float f; } c; c.i = ((unsigned)u) << 16; return c.f;
}
__device__ __forceinline__ u16 f2bf(float f) {
  union { float f; unsigned i; } c; c.f = f;
  unsigned x = c.i;
  return (u16)((x + 0x7fffu + ((x >> 16) & 1u)) >> 16);
}

// async global->LDS, 16B per lane (dest = wave-uniform base + lane*16)
__device__ __forceinline__ void gload16(const u16* g, u16* l) {
#if defined(__has_builtin) && __has_builtin(__builtin_amdgcn_global_load_lds)
  __builtin_amdgcn_global_load_lds(
      (const __attribute__((address_space(1))) void*)g,
      (__attribute__((address_space(3))) void*)l, 16, 0, 0);
#else
  *(short8*)l = *(const short8*)g;
#endif
}

// ===========================================================================
// PACKED LAYOUT (u16 indices; lane = qq*16 + rr, qq=lane>>4, rr=lane&15):
//   P[(rf*64 + kc)*512 + lane*8 + j] = T[rf*16 + rr][kc*32 + qq*8 + j]
// i.e. each (row-frag, k-subtile) = one contiguous 1KB chunk in MFMA lane
// order.  Consumers read chunks as contiguous 1KB wave loads (coalesced),
// gload_lds dest stays linear, and LDS fragment reads are conflict-free.
// Qp/Kp/Vp keep their existing (equivalent) frag-packed layouts.
// ===========================================================================

// ---------------------------------------------------------------------------
// cvt_pack: fp32 -> bf16 + frag-pack of x, Wq, Wk, Wv, Wo.
// Block = one (row-frag, 128-col group) = 4 chunks.  Coalesced fp32 reads,
// LDS transpose, contiguous 1KB packed writes.  Grid 6656 = 416 rf * 16.
// ---------------------------------------------------------------------------
__global__ __launch_bounds__(256) void cvt_pack(const float* __restrict__ x,
                                                const float* __restrict__ wq,
                                                const float* __restrict__ wk,
                                                const float* __restrict__ wv,
                                                const float* __restrict__ wo,
                                                u16* __restrict__ ws) {
  __shared__ __align__(16) u16 Ls[2048];
  const int tid = threadIdx.x;
  const int rfg = blockIdx.x >> 4;
  const int kcg = blockIdx.x & 15;
  const float* src; u16* dst; int lrf;
  if      (rfg < 128) { src = x;  dst = ws + OFF_X;  lrf = rfg; }
  else if (rfg < 256) { src = wq; dst = ws + OFF_WQ; lrf = rfg - 128; }
  else if (rfg < 272) { src = wk; dst = ws + OFF_WK; lrf = rfg - 256; }
  else if (rfg < 288) { src = wv; dst = ws + OFF_WV; lrf = rfg - 272; }
  else                { src = wo; dst = ws + OFF_WO; lrf = rfg - 288; }

  const int rr = tid >> 4, cb = tid & 15;       // row 0..15, col-8-block 0..15
  const float* s = src + (size_t)(lrf * 16 + rr) * DIM + kcg * 128 + cb * 8;
  float4 v0 = ((const float4*)s)[0];
  float4 v1 = ((const float4*)s)[1];
  ushort4 o0, o1;
  o0.x = f2bf(v0.x); o0.y = f2bf(v0.y); o0.z = f2bf(v0.z); o0.w = f2bf(v0.w);
  o1.x = f2bf(v1.x); o1.y = f2bf(v1.y); o1.z = f2bf(v1.z); o1.w = f2bf(v1.w);
  const int ch = cb >> 2, qq = cb & 3;
  u16* lp = &Ls[ch * 512 + (qq * 16 + rr) * 8];
  ((ushort4*)lp)[0] = o0;
  ((ushort4*)lp)[1] = o1;
  __syncthreads();
  const int och = tid >> 6, lane = tid & 63;
  *(short8*)(dst + ((size_t)(lrf * 64 + kcg * 4 + och)) * 512 + lane * 8) =
      *(const short8*)&Ls[och * 512 + lane * 8];
}

// ===========================================================================
// ATTENTION FRAG-PACKED LAYOUTS (unchanged):
//  Qp: [(h*64 + sq)*4 + i*2 + c]*512 + lane*8 + j
//  Kp: [((kvh*32 + kt)*8) + t*2 + c]*512 + lane*8 + j
//  Vp: [((kvh*32 + kt)*8) + s*4 + t]*512 + lane*8 + j
// ===========================================================================

// ---------------------------------------------------------------------------
// Fused QKV projection GEMM, 64x128 tiles, BK=64, packed sources, RoPE fused.
// Grid 640: tm = bid&31, tn = bid>>5 (0..19): 0..15 Q; 16..17 K; 18..19 V.
// ---------------------------------------------------------------------------
__global__ __launch_bounds__(256) void gemm_qkv(const u16* __restrict__ xp,
                                                const u16* __restrict__ Wqp,
                                                const u16* __restrict__ Wkp,
                                                const u16* __restrict__ Wvp,
                                                const float* __restrict__ cs,
                                                const float* __restrict__ sn,
                                                u16* __restrict__ Qp,
                                                u16* __restrict__ Kp,
                                                u16* __restrict__ Vp) {
  __shared__ __align__(16) u16 As[8 * 512];    // 4 row-frags x 2 k-subtiles
  __shared__ __align__(16) u16 Bs[16 * 512];   // 8 row-frags x 2 k-subtiles
  const int tid  = threadIdx.x;
  const int lane = tid & 63;
  const int w    = tid >> 6;
  const int r    = lane & 15, q = lane >> 4;
  const int tm = blockIdx.x & 31;
  const int tn = blockIdx.x >> 5;   // 0..19
  const int wm = w & 1, wn = w >> 1;

  const u16* Wp; int rfB0;
  if (tn < 16)      { Wp = Wqp; rfB0 = tn * 8; }
  else if (tn < 18) { Wp = Wkp; rfB0 = (tn - 16) * 8; }
  else              { Wp = Wvp; rfB0 = (tn - 18) * 8; }
  const int rfA0 = tm * 4;

  // per-wave chunk sources: chunk ch = f*2 + c; wave w serves A:{w,w+4},
  // B:{w,w+4,w+8,w+12}.  Each gload16 = one contiguous 1KB wave read.
  const int cA0 = w, cA1 = w + 4;
  const u16* aS0 = xp + ((size_t)(rfA0 + (cA0 >> 1)) * 64 + (cA0 & 1)) * 512 + lane * 8;
  const u16* aS1 = xp + ((size_t)(rfA0 + (cA1 >> 1)) * 64 + (cA1 & 1)) * 512 + lane * 8;
  const u16* bS[4];
#pragma unroll
  for (int j = 0; j < 4; ++j) {
    int ch = w + 4 * j;
    bS[j] = Wp + ((size_t)(rfB0 + (ch >> 1)) * 64 + (ch & 1)) * 512 + lane * 8;
  }

  floatx4 acc[2][4];
#pragma unroll
  for (int a = 0; a < 2; ++a)
#pragma unroll
    for (int b = 0; b < 4; ++b) acc[a][b] = (floatx4){0.f, 0.f, 0.f, 0.f};

  for (int kc0 = 0; kc0 < 64; kc0 += 2) {
    const size_t ko = (size_t)kc0 * 512;
    __syncthreads();
    gload16(aS0 + ko, &As[cA0 * 512 + lane * 8]);
    gload16(aS1 + ko, &As[cA1 * 512 + lane * 8]);
#pragma unroll
    for (int j = 0; j < 4; ++j)
      gload16(bS[j] + ko, &Bs[(w + 4 * j) * 512 + lane * 8]);
    __syncthreads();

    short8 af[2][2], bf[4][2];
#pragma unroll
    for (int mi = 0; mi < 2; ++mi)
#pragma unroll
      for (int c = 0; c < 2; ++c)
        af[mi][c] = *(const short8*)&As[((wm * 2 + mi) * 2 + c) * 512 + lane * 8];
#pragma unroll
    for (int nj = 0; nj < 4; ++nj)
#pragma unroll
      for (int c = 0; c < 2; ++c)
        bf[nj][c] = *(const short8*)&Bs[((wn * 4 + nj) * 2 + c) * 512 + lane * 8];
#pragma unroll
    for (int c = 0; c < 2; ++c)
#pragma unroll
      for (int mi = 0; mi < 2; ++mi)
#pragma unroll
        for (int nj = 0; nj < 4; ++nj)
          acc[mi][nj] = __builtin_amdgcn_mfma_f32_16x16x32_bf16(af[mi][c], bf[nj][c], acc[mi][nj], 0, 0, 0);
  }

  if (tn < 18) {
    const int head = (tn < 16) ? (tn * 2 + wn) : ((tn - 16) * 2 + wn);
#pragma unroll
    for (int mi = 0; mi < 2; ++mi)
#pragma unroll
      for (int g = 0; g < 4; ++g) {
        int row = tm * 64 + wm * 32 + mi * 16 + 4 * q + g;   // token
        const float* crow  = cs + (size_t)row * 64;
        const float* srow2 = sn + (size_t)row * 64;
#pragma unroll
        for (int nj = 0; nj < 2; ++nj) {
          int d = nj * 16 + r;               // head-dim 0..31 (pairs with d+32)
          float x0 = acc[mi][nj][g];
          float x1 = acc[mi][nj + 2][g];
          float o0 = x0 * crow[d]      - x1 * srow2[d];
          float o1 = x1 * crow[d + 32] + x0 * srow2[d + 32];
          int qq = d >> 3, j = d & 7;
          int lslot = (qq * 16 + (row & 15)) * 8 + j;
          if (tn < 16) {
            int sq = row >> 5, ii = (row >> 4) & 1;
            size_t base = ((size_t)(head * 64 + sq) * 4 + ii * 2) * 512 + lslot;
            Qp[base]       = f2bf(o0);
            Qp[base + 512] = f2bf(o1);
          } else {
            int kt2 = row >> 6, t = (row >> 4) & 3;
            size_t base = ((size_t)(head * 32 + kt2) * 8 + t * 2) * 512 + lslot;
            Kp[base]       = f2bf(o0);
            Kp[base + 512] = f2bf(o1);
          }
        }
      }
  } else {
#pragma unroll
    for (int mi = 0; mi < 2; ++mi)
#pragma unroll
      for (int nj = 0; nj < 4; ++nj) {
        int col  = (tn - 18) * 128 + wn * 64 + nj * 16 + r;   // dim 0..255
        int kvh  = col >> 6;
        int t    = (col & 63) >> 4;
        int rr   = col & 15;
        int row0 = tm * 64 + wm * 32 + mi * 16 + 4 * q;       // token
        int kt2  = row0 >> 6;
        int wk   = row0 & 63;
        int s    = wk >> 5;
        int qq   = (wk & 31) >> 3;
        int j0   = wk & 7;
        uint2 pk;
        pk.x = (unsigned)f2bf(acc[mi][nj][0]) | ((unsigned)f2bf(acc[mi][nj][1]) << 16);
        pk.y = (unsigned)f2bf(acc[mi][nj][2]) | ((unsigned)f2bf(acc[mi][nj][3]) << 16);
        size_t idx = ((size_t)(kvh * 32 + kt2) * 8 + s * 4 + t) * 512 + (qq * 16 + rr) * 8 + j0;
        *(uint2*)(Vp + idx) = pk;
      }
  }
}

// ---------------------------------------------------------------------------
// Output GEMM, 64x128 tiles, BK=64, packed A (Ybp) + packed B (Wop), fp32 out.
// Grid 512: tn = bid&15, tm = bid>>4.
// ---------------------------------------------------------------------------
__global__ __launch_bounds__(256) void gemm_out(const u16* __restrict__ Ap,
                                                const u16* __restrict__ Wp,
                                                float* __restrict__ C) {
  __shared__ __align__(16) u16 As[8 * 512];
  __shared__ __align__(16) u16 Bs[16 * 512];
  const int tid  = threadIdx.x;
  const int lane = tid & 63;
  const int w    = tid >> 6;
  const int r    = lane & 15, q = lane >> 4;
  const int tn = blockIdx.x & 15;
  const int tm = blockIdx.x >> 4;
  const int wm = w & 1, wn = w >> 1;

  const int rfA0 = tm * 4, rfB0 = tn * 8;
  const int cA0 = w, cA1 = w + 4;
  const u16* aS0 = Ap + ((size_t)(rfA0 + (cA0 >> 1)) * 64 + (cA0 & 1)) * 512 + lane * 8;
  const u16* aS1 = Ap + ((size_t)(rfA0 + (cA1 >> 1)) * 64 + (cA1 & 1)) * 512 + lane * 8;
  const u16* bS[4];
#pragma unroll
  for (int j = 0; j < 4; ++j) {
    int ch = w + 4 * j;
    bS[j] = Wp + ((size_t)(rfB0 + (ch >> 1)) * 64 + (ch & 1)) * 512 + lane * 8;
  }

  floatx4 acc[2][4];
#pragma unroll
  for (int a = 0; a < 2; ++a)
#pragma unroll
    for (int b = 0; b < 4; ++b) acc[a][b] = (floatx4){0.f, 0.f, 0.f, 0.f};

  for (int kc0 = 0; kc0 < 64; kc0 += 2) {
    const size_t ko = (size_t)kc0 * 512;
    __syncthreads();
    gload16(aS0 + ko, &As[cA0 * 512 + lane * 8]);
    gload16(aS1 + ko, &As[cA1 * 512 + lane * 8]);
#pragma unroll
    for (int j = 0; j < 4; ++j)
      gload16(bS[j] + ko, &Bs[(w + 4 * j) * 512 + lane * 8]);
    __syncthreads();

    short8 af[2][2], bf[4][2];
#pragma unroll
    for (int mi = 0; mi < 2; ++mi)
#pragma unroll
      for (int c = 0; c < 2; ++c)
        af[mi][c] = *(const short8*)&As[((wm * 2 + mi) * 2 + c) * 512 + lane * 8];
#pragma unroll
    for (int nj = 0; nj < 4; ++nj)
#pragma unroll
      for (int c = 0; c < 2; ++c)
        bf[nj][c] = *(const short8*)&Bs[((wn * 4 + nj) * 2 + c) * 512 + lane * 8];
#pragma unroll
    for (int c = 0; c < 2; ++c)
#pragma unroll
      for (int mi = 0; mi < 2; ++mi)
#pragma unroll
        for (int nj = 0; nj < 4; ++nj)
          acc[mi][nj] = __builtin_amdgcn_mfma_f32_16x16x32_bf16(af[mi][c], bf[nj][c], acc[mi][nj], 0, 0, 0);
  }

#pragma unroll
  for (int mi = 0; mi < 2; ++mi)
#pragma unroll
    for (int g = 0; g < 4; ++g) {
      int row = tm * 64 + wm * 32 + mi * 16 + 4 * q + g;
#pragma unroll
      for (int nj = 0; nj < 4; ++nj)
        C[(size_t)row * DIM + tn * 128 + wn * 64 + nj * 16 + r] = acc[mi][nj][g];
    }
}

// ---------------------------------------------------------------------------
// Balanced pair-scheduled MFMA flash attention (R3-proven).  Only change:
// the output Y is written in PACKED layout so gemm_out's staging is 1KB
// contiguous wave reads.
// ---------------------------------------------------------------------------
__global__ __launch_bounds__(128, 2) void attn_mfma(const u16* __restrict__ Qp,
                                                    const u16* __restrict__ Kp,
                                                    const u16* __restrict__ Vp,
                                                    u16* __restrict__ Ybp) {
  __shared__ __align__(16) u16 Pl[2][32][72];
  __shared__ float OcA[32][66];   // wave1's partial for q-block A
  __shared__ float OcB[32][66];   // wave0's partial for q-block B
  __shared__ float LcA[2][64], LcB[2][64];
  const int tid  = threadIdx.x;
  const int lane = tid & 63;
  const int w    = tid >> 6;       // 0 or 1
  const int r    = lane & 15;
  const int q    = lane >> 4;
  const int p    = blockIdx.x;     // 0..31 pair index
  const int h    = blockIdx.y;
  const int kvh  = h >> 3;
  const int jA   = 63 - p;         // heavy q-block
  const int jB   = p;              // light q-block
  const int baseqA = jA * 32, baseqB = jB * 32;
  const int tA = (jA >> 1) + 1, tB = (jB >> 1) + 1;   // tile counts
  const int ktmaxA = tA - 1, ktmaxB = tB - 1;

  // Q frags: one 1KB wave read each (sq == j for 32-row q-blocks)
  short8 qfA[2][2], qfB[2][2];
#pragma unroll
  for (int i = 0; i < 2; ++i)
#pragma unroll
    for (int c = 0; c < 2; ++c) {
      qfA[i][c] = *(const short8*)(Qp + ((size_t)(h * 64 + jA) * 4 + i * 2 + c) * 512 + lane * 8);
      qfB[i][c] = *(const short8*)(Qp + ((size_t)(h * 64 + jB) * 4 + i * 2 + c) * 512 + lane * 8);
    }

  floatx4 OA[2][4], OB[2][4];
  float lsumA[2], lsumB[2];
#pragma unroll
  for (int i = 0; i < 2; ++i) {
    lsumA[i] = 0.f; lsumB[i] = 0.f;
#pragma unroll
    for (int t = 0; t < 4; ++t) {
      OA[i][t] = (floatx4){0.f, 0.f, 0.f, 0.f};
      OB[i][t] = (floatx4){0.f, 0.f, 0.f, 0.f};
    }
  }

  const u16* Kbase = Kp + (size_t)(kvh * 32) * 8 * 512;
  const u16* Vbase = Vp + (size_t)(kvh * 32) * 8 * 512;

  auto loadK = [&](int kt, short8 (&kf)[4][2]) {
    const u16* kb = Kbase + (size_t)kt * 8 * 512 + lane * 8;
#pragma unroll
    for (int t = 0; t < 4; ++t) {
      kf[t][0] = *(const short8*)(kb + (t * 2 + 0) * 512);
      kf[t][1] = *(const short8*)(kb + (t * 2 + 1) * 512);
    }
  };

  auto body = [&](int kt, int ktmax, int baseq,
                  short8 (&qf)[2][2], floatx4 (&O)[2][4], float (&lsum)[2],
                  short8 (&kc)[4][2], short8 (&kn)[4][2]) {
    // V for CURRENT tile: issued first, consumed at the bottom
    short8 vb[2][4];
    {
      const u16* vbp = Vbase + (size_t)kt * 8 * 512 + lane * 8;
#pragma unroll
      for (int s = 0; s < 2; ++s)
#pragma unroll
        for (int t = 0; t < 4; ++t)
          vb[s][t] = *(const short8*)(vbp + (s * 4 + t) * 512);
    }

    // K for this wave's next tile (kt+2), clamped, branchless
    loadK(kt + 2 <= ktmax ? kt + 2 : ktmax, kn);

    // ---- S^T = K Q^T ----
    floatx4 ST[2][4];
#pragma unroll
    for (int i = 0; i < 2; ++i)
#pragma unroll
      for (int t = 0; t < 4; ++t) ST[i][t] = (floatx4){0.f, 0.f, 0.f, 0.f};
#pragma unroll
    for (int t = 0; t < 4; ++t)
#pragma unroll
      for (int i = 0; i < 2; ++i) {
        ST[i][t] = __builtin_amdgcn_mfma_f32_16x16x32_bf16(kc[t][0], qf[i][0], ST[i][t], 0, 0, 0);
        ST[i][t] = __builtin_amdgcn_mfma_f32_16x16x32_bf16(kc[t][1], qf[i][1], ST[i][t], 0, 0, 0);
      }

    // ---- causal mask (only the last tile of this q-block can clip) ----
    if (kt == ktmax) {
#pragma unroll
      for (int i = 0; i < 2; ++i) {
        int qrow = baseq + 16 * i + r;
#pragma unroll
        for (int t = 0; t < 4; ++t) {
          int key = kt * 64 + 16 * t + 4 * q;
#pragma unroll
          for (int g = 0; g < 4; ++g)
            if (key + g > qrow) ST[i][t][g] = -1e30f;
        }
      }
    }

    // ---- p = exp(scale*s); partial row-sums; packed P -> LDS ----
#pragma unroll
    for (int i = 0; i < 2; ++i)
#pragma unroll
      for (int t = 0; t < 4; ++t) {
        float p0 = __expf(0.125f * ST[i][t][0]);
        float p1 = __expf(0.125f * ST[i][t][1]);
        float p2 = __expf(0.125f * ST[i][t][2]);
        float p3 = __expf(0.125f * ST[i][t][3]);
        lsum[i] += (p0 + p1) + (p2 + p3);
        uint2 pk;
        pk.x = (unsigned)f2bf(p0) | ((unsigned)f2bf(p1) << 16);
        pk.y = (unsigned)f2bf(p2) | ((unsigned)f2bf(p3) << 16);
        *(uint2*)&Pl[w][16 * i + r][16 * t + 4 * q] = pk;   // ds_write_b64
      }

    // ---- O += P V ----
#pragma unroll
    for (int s = 0; s < 2; ++s)
#pragma unroll
      for (int i = 0; i < 2; ++i) {
        short8 pa = *(const short8*)&Pl[w][16 * i + r][32 * s + 8 * q];
#pragma unroll
        for (int t = 0; t < 4; ++t)
          O[i][t] = __builtin_amdgcn_mfma_f32_16x16x32_bf16(pa, vb[s][t], O[i][t], 0, 0, 0);
      }
  };

  auto runloop = [&](int start, int ktmax, int baseq,
                     short8 (&qf)[2][2], floatx4 (&O)[2][4], float (&lsum)[2]) {
    if (start > ktmax) return;
    short8 kA[4][2], kB[4][2];
    loadK(start, kA);
    for (int kt = start; kt <= ktmax; kt += 4) {
      body(kt, ktmax, baseq, qf, O, lsum, kA, kB);
      if (kt + 2 <= ktmax) body(kt + 2, ktmax, baseq, qf, O, lsum, kB, kA);
    }
  };

  // Wave w takes items [w::2] of the combined list [A-tiles..., B-tiles...]
  runloop(w, ktmaxA, baseqA, qfA, OA, lsumA);
  const int sB = (w + tA) & 1;   // parity continuation into the B-tiles
  runloop(sB, ktmaxB, baseqB, qfB, OB, lsumB);

  // ---- cross-wave combine ----
  if (w == 1) {
#pragma unroll
    for (int i = 0; i < 2; ++i) {
#pragma unroll
      for (int t = 0; t < 4; ++t)
#pragma unroll
        for (int g = 0; g < 4; ++g)
          OcA[(i * 4 + t) * 4 + g][lane] = OA[i][t][g];
      LcA[i][lane] = lsumA[i];
    }
  } else {
#pragma unroll
    for (int i = 0; i < 2; ++i) {
#pragma unroll
      for (int t = 0; t < 4; ++t)
#pragma unroll
        for (int g = 0; g < 4; ++g)
          OcB[(i * 4 + t) * 4 + g][lane] = OB[i][t][g];
      LcB[i][lane] = lsumB[i];
    }
  }
  __syncthreads();

  // finalize: normalize and store to PACKED Yb layout:
  //   row = baseq+16i+4q+g, col = h*64 + 16t + r
  //   idx = ((row>>4)*64 + h*2 + (t>>1))*512 + ((2*(t&1)+(r>>3))*16 + (row&15))*8 + (r&7)
  auto finalize = [&](int baseq, floatx4 (&O)[2][4], float (&lsum)[2]) {
#pragma unroll
    for (int i = 0; i < 2; ++i) {
      lsum[i] += __shfl_xor(lsum[i], 16);
      lsum[i] += __shfl_xor(lsum[i], 32);   // lane(q,r) holds sum for row r
    }
#pragma unroll
    for (int i = 0; i < 2; ++i) {
      float inv[4];
#pragma unroll
      for (int g = 0; g < 4; ++g)
        inv[g] = 1.f / __shfl(lsum[i], 4 * q + g);
#pragma unroll
      for (int g = 0; g < 4; ++g) {
        int rowi = baseq + 16 * i + 4 * q + g;
        size_t rbase = ((size_t)(rowi >> 4) * 64 + h * 2) * 512 +
                       (((r >> 3)) * 16 + (rowi & 15)) * 8 + (r & 7);
        Ybp[rbase]       = f2bf(O[i][0][g] * inv[g]);   // t=0
        Ybp[rbase + 256] = f2bf(O[i][1][g] * inv[g]);   // t=1
        Ybp[rbase + 512] = f2bf(O[i][2][g] * inv[g]);   // t=2
        Ybp[rbase + 768] = f2bf(O[i][3][g] * inv[g]);   // t=3
      }
    }
  };

  if (w == 0) {
#pragma unroll
    for (int i = 0; i < 2; ++i) {
#pragma unroll
      for (int t = 0; t < 4; ++t)
#pragma unroll
        for (int g = 0; g < 4; ++g)
          OA[i][t][g] += OcA[(i * 4 + t) * 4 + g][lane];
      lsumA[i] += LcA[i][lane];
    }
    finalize(baseqA, OA, lsumA);
  } else {
#pragma unroll
    for (int i = 0; i < 2; ++i) {
#pragma unroll
      for (int t = 0; t < 4; ++t)
#pragma unroll
        for (int g = 0; g < 4; ++g)
          OB[i][t][g] += OcB[(i * 4 + t) * 4 + g][lane];
      lsumB[i] += LcB[i][lane];
    }
    finalize(baseqB, OB, lsumB);
  }
}

// ---------------------------------------------------------------------------
extern "C" void kernel_launch(void* const* d_in, const int* in_sizes, int n_in,
                              void* d_out, int out_size, void* d_ws, size_t ws_size,
                              hipStream_t stream) {
  const float* x  = (const float*)d_in[0];
  const float* Wq = (const float*)d_in[1];
  const float* Wk = (const float*)d_in[2];
  const float* Wv = (const float*)d_in[3];
  const float* Wo = (const float*)d_in[4];
  const float* cs = (const float*)d_in[5];
  const float* sn = (const float*)d_in[6];

  u16* ws  = (u16*)d_ws;
  u16* xp  = ws + OFF_X;
  u16* Wqp = ws + OFF_WQ;
  u16* Wkp = ws + OFF_WK;
  u16* Wvp = ws + OFF_WV;
  u16* Wop = ws + OFF_WO;
  u16* Qp  = ws + OFF_QP;
  u16* Kp  = ws + OFF_KP;
  u16* Vp  = ws + OFF_VP;
  u16* Ybp = ws + OFF_YB;

  // fp32 -> bf16 + frag-pack (x + 4 weights)
  cvt_pack<<<dim3(6656), 256, 0, stream>>>(x, Wq, Wk, Wv, Wo, ws);

  // Fused QKV projection + RoPE, packed in, frag-packed out
  gemm_qkv<<<dim3(640), 256, 0, stream>>>(xp, Wqp, Wkp, Wvp, cs, sn, Qp, Kp, Vp);

  // Balanced pair-scheduled attention, writes packed Yb
  attn_mfma<<<dim3(32, 32), 128, 0, stream>>>(Qp, Kp, Vp, Ybp);

  // Output projection (packed A and B, fp32 straight to d_out)
  gemm_out<<<dim3(512), 256, 0, stream>>>(Ybp, Wop, (float*)d_out);
}

// Round 10
// 190.240 us; speedup vs baseline: 1.4828x; 1.0096x over previous
//
#include <hip/hip_runtime.h>

typedef unsigned short u16;
typedef __attribute__((ext_vector_type(8))) short short8;
typedef __attribute__((ext_vector_type(4))) float floatx4;

#define N_TOK 2048
#define DIM   2048
#define NH    32
#define NKVH  4
#define HD    64
#define KVD   256

// packed-region offsets in the u16 workspace
#define OFF_X   0
#define OFF_WQ  4194304
#define OFF_WK  8388608
#define OFF_WV  8912896
#define OFF_WO  9437184
#define OFF_QP  13631488
#define OFF_KP  17825792
#define OFF_VP  18350080
#define OFF_YB  18874368

__device__ __forceinline__ float bf2f(u16 u) {
  union { unsigned i; float f; } c; c.i = ((unsigned)u) << 16; return c.f;
}
__device__ __forceinline__ u16 f2bf(float f) {
  union { float f; unsigned i; } c; c.f = f;
  unsigned x = c.i;
  return (u16)((x + 0x7fffu + ((x >> 16) & 1u)) >> 16);
}

// async global->LDS, 16B per lane (dest = wave-uniform base + lane*16)
__device__ __forceinline__ void gload16(const u16* g, u16* l) {
#if defined(__has_builtin) && __has_builtin(__builtin_amdgcn_global_load_lds)
  __builtin_amdgcn_global_load_lds(
      (const __attribute__((address_space(1))) void*)g,
      (__attribute__((address_space(3))) void*)l, 16, 0, 0);
#else
  *(short8*)l = *(const short8*)g;
#endif
}

// ===========================================================================
// PACKED LAYOUT (u16 indices; lane = qq*16 + rr, qq=lane>>4, rr=lane&15):
//   P[(rf*64 + kc)*512 + lane*8 + j] = T[rf*16 + rr][kc*32 + qq*8 + j]
// Each (row-frag, k-subtile) = one contiguous 1KB chunk in MFMA lane order.
// Consumers read chunks as contiguous 1KB wave loads (coalesced), gload_lds
// dest stays linear, LDS fragment reads are conflict-free.
// ===========================================================================

// ---------------------------------------------------------------------------
// cvt_pack: fp32 -> bf16 + frag-pack of x, Wq, Wk, Wv, Wo.
// ---------------------------------------------------------------------------
__global__ __launch_bounds__(256) void cvt_pack(const float* __restrict__ x,
                                                const float* __restrict__ wq,
                                                const float* __restrict__ wk,
                                                const float* __restrict__ wv,
                                                const float* __restrict__ wo,
                                                u16* __restrict__ ws) {
  __shared__ __align__(16) u16 Ls[2048];
  const int tid = threadIdx.x;
  const int rfg = blockIdx.x >> 4;
  const int kcg = blockIdx.x & 15;
  const float* src; u16* dst; int lrf;
  if      (rfg < 128) { src = x;  dst = ws + OFF_X;  lrf = rfg; }
  else if (rfg < 256) { src = wq; dst = ws + OFF_WQ; lrf = rfg - 128; }
  else if (rfg < 272) { src = wk; dst = ws + OFF_WK; lrf = rfg - 256; }
  else if (rfg < 288) { src = wv; dst = ws + OFF_WV; lrf = rfg - 272; }
  else                { src = wo; dst = ws + OFF_WO; lrf = rfg - 288; }

  const int rr = tid >> 4, cb = tid & 15;       // row 0..15, col-8-block 0..15
  const float* s = src + (size_t)(lrf * 16 + rr) * DIM + kcg * 128 + cb * 8;
  float4 v0 = ((const float4*)s)[0];
  float4 v1 = ((const float4*)s)[1];
  ushort4 o0, o1;
  o0.x = f2bf(v0.x); o0.y = f2bf(v0.y); o0.z = f2bf(v0.z); o0.w = f2bf(v0.w);
  o1.x = f2bf(v1.x); o1.y = f2bf(v1.y); o1.z = f2bf(v1.z); o1.w = f2bf(v1.w);
  const int ch = cb >> 2, qq = cb & 3;
  u16* lp = &Ls[ch * 512 + (qq * 16 + rr) * 8];
  ((ushort4*)lp)[0] = o0;
  ((ushort4*)lp)[1] = o1;
  __syncthreads();
  const int och = tid >> 6, lane = tid & 63;
  *(short8*)(dst + ((size_t)(lrf * 64 + kcg * 4 + och)) * 512 + lane * 8) =
      *(const short8*)&Ls[och * 512 + lane * 8];
}

// ===========================================================================
// ATTENTION FRAG-PACKED LAYOUTS (unchanged):
//  Qp: [(h*64 + sq)*4 + i*2 + c]*512 + lane*8 + j
//  Kp: [((kvh*32 + kt)*8) + t*2 + c]*512 + lane*8 + j
//  Vp: [((kvh*32 + kt)*8) + s*4 + t]*512 + lane*8 + j
// ===========================================================================
// GEMM K-loop: 2-deep double-buffer, counted vmcnt (never 0 in main loop):
//   prologue: stage(b0,kt=0); stage(b1,kt=1)        (12 loads in flight)
//   iter kt:  s_waitcnt vmcnt(6)                    (oldest stage landed)
//             s_barrier; compute buf kt%2; s_barrier
//             stage(kt+2) into buf kt%2             (back to 12 in flight)
// Tail: vmcnt(0) at kt=31.  Schedule correctness-proven in R6 (3-buf variant);
// loads are now contiguous 1KB wave reads (R9), so in-flight stages are cheap.
// ===========================================================================

// ---------------------------------------------------------------------------
// Fused QKV projection GEMM, 64x128 tiles, BK=64, packed sources, RoPE fused.
// Grid 640: tm = bid&31, tn = bid>>5 (0..19): 0..15 Q; 16..17 K; 18..19 V.
// ---------------------------------------------------------------------------
__global__ __launch_bounds__(256) void gemm_qkv(const u16* __restrict__ xp,
                                                const u16* __restrict__ Wqp,
                                                const u16* __restrict__ Wkp,
                                                const u16* __restrict__ Wvp,
                                                const float* __restrict__ cs,
                                                const float* __restrict__ sn,
                                                u16* __restrict__ Qp,
                                                u16* __restrict__ Kp,
                                                u16* __restrict__ Vp) {
  __shared__ __align__(16) u16 As[2][8 * 512];
  __shared__ __align__(16) u16 Bs[2][16 * 512];
  const int tid  = threadIdx.x;
  const int lane = tid & 63;
  const int w    = tid >> 6;
  const int r    = lane & 15, q = lane >> 4;
  const int tm = blockIdx.x & 31;
  const int tn = blockIdx.x >> 5;   // 0..19
  const int wm = w & 1, wn = w >> 1;

  const u16* Wp; int rfB0;
  if (tn < 16)      { Wp = Wqp; rfB0 = tn * 8; }
  else if (tn < 18) { Wp = Wkp; rfB0 = (tn - 16) * 8; }
  else              { Wp = Wvp; rfB0 = (tn - 18) * 8; }
  const int rfA0 = tm * 4;

  const int cA0 = w, cA1 = w + 4;
  const u16* aS0 = xp + ((size_t)(rfA0 + (cA0 >> 1)) * 64 + (cA0 & 1)) * 512 + lane * 8;
  const u16* aS1 = xp + ((size_t)(rfA0 + (cA1 >> 1)) * 64 + (cA1 & 1)) * 512 + lane * 8;
  const u16* bS[4];
#pragma unroll
  for (int j = 0; j < 4; ++j) {
    int ch = w + 4 * j;
    bS[j] = Wp + ((size_t)(rfB0 + (ch >> 1)) * 64 + (ch & 1)) * 512 + lane * 8;
  }

  floatx4 acc[2][4];
#pragma unroll
  for (int a = 0; a < 2; ++a)
#pragma unroll
    for (int b = 0; b < 4; ++b) acc[a][b] = (floatx4){0.f, 0.f, 0.f, 0.f};

  auto stage = [&](int b, int kt) {          // 6 contiguous 1KB wave loads
    const size_t ko = (size_t)(kt * 2) * 512;
    gload16(aS0 + ko, &As[b][cA0 * 512 + lane * 8]);
    gload16(aS1 + ko, &As[b][cA1 * 512 + lane * 8]);
#pragma unroll
    for (int j = 0; j < 4; ++j)
      gload16(bS[j] + ko, &Bs[b][(w + 4 * j) * 512 + lane * 8]);
  };

  stage(0, 0);
  stage(1, 1);
  int cb = 0;
  for (int kt = 0; kt < 32; ++kt) {
    if (kt < 31) asm volatile("s_waitcnt vmcnt(6)" ::: "memory");
    else         asm volatile("s_waitcnt vmcnt(0)" ::: "memory");
    __builtin_amdgcn_s_barrier();
    __builtin_amdgcn_sched_barrier(0);

    short8 af[2][2], bf[4][2];
#pragma unroll
    for (int mi = 0; mi < 2; ++mi)
#pragma unroll
      for (int c = 0; c < 2; ++c)
        af[mi][c] = *(const short8*)&As[cb][((wm * 2 + mi) * 2 + c) * 512 + lane * 8];
#pragma unroll
    for (int nj = 0; nj < 4; ++nj)
#pragma unroll
      for (int c = 0; c < 2; ++c)
        bf[nj][c] = *(const short8*)&Bs[cb][((wn * 4 + nj) * 2 + c) * 512 + lane * 8];
#pragma unroll
    for (int c = 0; c < 2; ++c)
#pragma unroll
      for (int mi = 0; mi < 2; ++mi)
#pragma unroll
        for (int nj = 0; nj < 4; ++nj)
          acc[mi][nj] = __builtin_amdgcn_mfma_f32_16x16x32_bf16(af[mi][c], bf[nj][c], acc[mi][nj], 0, 0, 0);

    __builtin_amdgcn_sched_barrier(0);
    __builtin_amdgcn_s_barrier();            // all waves done reading buf cb
    if (kt + 2 < 32) stage(cb, kt + 2);
    cb ^= 1;
  }

  if (tn < 18) {
    const int head = (tn < 16) ? (tn * 2 + wn) : ((tn - 16) * 2 + wn);
#pragma unroll
    for (int mi = 0; mi < 2; ++mi)
#pragma unroll
      for (int g = 0; g < 4; ++g) {
        int row = tm * 64 + wm * 32 + mi * 16 + 4 * q + g;   // token
        const float* crow  = cs + (size_t)row * 64;
        const float* srow2 = sn + (size_t)row * 64;
#pragma unroll
        for (int nj = 0; nj < 2; ++nj) {
          int d = nj * 16 + r;               // head-dim 0..31 (pairs with d+32)
          float x0 = acc[mi][nj][g];
          float x1 = acc[mi][nj + 2][g];
          float o0 = x0 * crow[d]      - x1 * srow2[d];
          float o1 = x1 * crow[d + 32] + x0 * srow2[d + 32];
          int qq = d >> 3, j = d & 7;
          int lslot = (qq * 16 + (row & 15)) * 8 + j;
          if (tn < 16) {
            int sq = row >> 5, ii = (row >> 4) & 1;
            size_t base = ((size_t)(head * 64 + sq) * 4 + ii * 2) * 512 + lslot;
            Qp[base]       = f2bf(o0);
            Qp[base + 512] = f2bf(o1);
          } else {
            int kt2 = row >> 6, t = (row >> 4) & 3;
            size_t base = ((size_t)(head * 32 + kt2) * 8 + t * 2) * 512 + lslot;
            Kp[base]       = f2bf(o0);
            Kp[base + 512] = f2bf(o1);
          }
        }
      }
  } else {
#pragma unroll
    for (int mi = 0; mi < 2; ++mi)
#pragma unroll
      for (int nj = 0; nj < 4; ++nj) {
        int col  = (tn - 18) * 128 + wn * 64 + nj * 16 + r;   // dim 0..255
        int kvh  = col >> 6;
        int t    = (col & 63) >> 4;
        int rr   = col & 15;
        int row0 = tm * 64 + wm * 32 + mi * 16 + 4 * q;       // token
        int kt2  = row0 >> 6;
        int wk   = row0 & 63;
        int s    = wk >> 5;
        int qq   = (wk & 31) >> 3;
        int j0   = wk & 7;
        uint2 pk;
        pk.x = (unsigned)f2bf(acc[mi][nj][0]) | ((unsigned)f2bf(acc[mi][nj][1]) << 16);
        pk.y = (unsigned)f2bf(acc[mi][nj][2]) | ((unsigned)f2bf(acc[mi][nj][3]) << 16);
        size_t idx = ((size_t)(kvh * 32 + kt2) * 8 + s * 4 + t) * 512 + (qq * 16 + rr) * 8 + j0;
        *(uint2*)(Vp + idx) = pk;
      }
  }
}

// ---------------------------------------------------------------------------
// Output GEMM, 64x128 tiles, BK=64, packed A (Ybp) + packed B (Wop), fp32 out.
// Same 2-deep counted-vmcnt pipeline.  Grid 512: tn = bid&15, tm = bid>>4.
// ---------------------------------------------------------------------------
__global__ __launch_bounds__(256) void gemm_out(const u16* __restrict__ Ap,
                                                const u16* __restrict__ Wp,
                                                float* __restrict__ C) {
  __shared__ __align__(16) u16 As[2][8 * 512];
  __shared__ __align__(16) u16 Bs[2][16 * 512];
  const int tid  = threadIdx.x;
  const int lane = tid & 63;
  const int w    = tid >> 6;
  const int r    = lane & 15, q = lane >> 4;
  const int tn = blockIdx.x & 15;
  const int tm = blockIdx.x >> 4;
  const int wm = w & 1, wn = w >> 1;

  const int rfA0 = tm * 4, rfB0 = tn * 8;
  const int cA0 = w, cA1 = w + 4;
  const u16* aS0 = Ap + ((size_t)(rfA0 + (cA0 >> 1)) * 64 + (cA0 & 1)) * 512 + lane * 8;
  const u16* aS1 = Ap + ((size_t)(rfA0 + (cA1 >> 1)) * 64 + (cA1 & 1)) * 512 + lane * 8;
  const u16* bS[4];
#pragma unroll
  for (int j = 0; j < 4; ++j) {
    int ch = w + 4 * j;
    bS[j] = Wp + ((size_t)(rfB0 + (ch >> 1)) * 64 + (ch & 1)) * 512 + lane * 8;
  }

  floatx4 acc[2][4];
#pragma unroll
  for (int a = 0; a < 2; ++a)
#pragma unroll
    for (int b = 0; b < 4; ++b) acc[a][b] = (floatx4){0.f, 0.f, 0.f, 0.f};

  auto stage = [&](int b, int kt) {
    const size_t ko = (size_t)(kt * 2) * 512;
    gload16(aS0 + ko, &As[b][cA0 * 512 + lane * 8]);
    gload16(aS1 + ko, &As[b][cA1 * 512 + lane * 8]);
#pragma unroll
    for (int j = 0; j < 4; ++j)
      gload16(bS[j] + ko, &Bs[b][(w + 4 * j) * 512 + lane * 8]);
  };

  stage(0, 0);
  stage(1, 1);
  int cb = 0;
  for (int kt = 0; kt < 32; ++kt) {
    if (kt < 31) asm volatile("s_waitcnt vmcnt(6)" ::: "memory");
    else         asm volatile("s_waitcnt vmcnt(0)" ::: "memory");
    __builtin_amdgcn_s_barrier();
    __builtin_amdgcn_sched_barrier(0);

    short8 af[2][2], bf[4][2];
#pragma unroll
    for (int mi = 0; mi < 2; ++mi)
#pragma unroll
      for (int c = 0; c < 2; ++c)
        af[mi][c] = *(const short8*)&As[cb][((wm * 2 + mi) * 2 + c) * 512 + lane * 8];
#pragma unroll
    for (int nj = 0; nj < 4; ++nj)
#pragma unroll
      for (int c = 0; c < 2; ++c)
        bf[nj][c] = *(const short8*)&Bs[cb][((wn * 4 + nj) * 2 + c) * 512 + lane * 8];
#pragma unroll
    for (int c = 0; c < 2; ++c)
#pragma unroll
      for (int mi = 0; mi < 2; ++mi)
#pragma unroll
        for (int nj = 0; nj < 4; ++nj)
          acc[mi][nj] = __builtin_amdgcn_mfma_f32_16x16x32_bf16(af[mi][c], bf[nj][c], acc[mi][nj], 0, 0, 0);

    __builtin_amdgcn_sched_barrier(0);
    __builtin_amdgcn_s_barrier();
    if (kt + 2 < 32) stage(cb, kt + 2);
    cb ^= 1;
  }

#pragma unroll
  for (int mi = 0; mi < 2; ++mi)
#pragma unroll
    for (int g = 0; g < 4; ++g) {
      int row = tm * 64 + wm * 32 + mi * 16 + 4 * q + g;
#pragma unroll
      for (int nj = 0; nj < 4; ++nj)
        C[(size_t)row * DIM + tn * 128 + wn * 64 + nj * 16 + r] = acc[mi][nj][g];
    }
}

// ---------------------------------------------------------------------------
// Balanced pair-scheduled MFMA flash attention (R3-proven), packed Yb output.
// ---------------------------------------------------------------------------
__global__ __launch_bounds__(128, 2) void attn_mfma(const u16* __restrict__ Qp,
                                                    const u16* __restrict__ Kp,
                                                    const u16* __restrict__ Vp,
                                                    u16* __restrict__ Ybp) {
  __shared__ __align__(16) u16 Pl[2][32][72];
  __shared__ float OcA[32][66];   // wave1's partial for q-block A
  __shared__ float OcB[32][66];   // wave0's partial for q-block B
  __shared__ float LcA[2][64], LcB[2][64];
  const int tid  = threadIdx.x;
  const int lane = tid & 63;
  const int w    = tid >> 6;       // 0 or 1
  const int r    = lane & 15;
  const int q    = lane >> 4;
  const int p    = blockIdx.x;     // 0..31 pair index
  const int h    = blockIdx.y;
  const int kvh  = h >> 3;
  const int jA   = 63 - p;         // heavy q-block
  const int jB   = p;              // light q-block
  const int baseqA = jA * 32, baseqB = jB * 32;
  const int tA = (jA >> 1) + 1, tB = (jB >> 1) + 1;   // tile counts
  const int ktmaxA = tA - 1, ktmaxB = tB - 1;

  // Q frags: one 1KB wave read each (sq == j for 32-row q-blocks)
  short8 qfA[2][2], qfB[2][2];
#pragma unroll
  for (int i = 0; i < 2; ++i)
#pragma unroll
    for (int c = 0; c < 2; ++c) {
      qfA[i][c] = *(const short8*)(Qp + ((size_t)(h * 64 + jA) * 4 + i * 2 + c) * 512 + lane * 8);
      qfB[i][c] = *(const short8*)(Qp + ((size_t)(h * 64 + jB) * 4 + i * 2 + c) * 512 + lane * 8);
    }

  floatx4 OA[2][4], OB[2][4];
  float lsumA[2], lsumB[2];
#pragma unroll
  for (int i = 0; i < 2; ++i) {
    lsumA[i] = 0.f; lsumB[i] = 0.f;
#pragma unroll
    for (int t = 0; t < 4; ++t) {
      OA[i][t] = (floatx4){0.f, 0.f, 0.f, 0.f};
      OB[i][t] = (floatx4){0.f, 0.f, 0.f, 0.f};
    }
  }

  const u16* Kbase = Kp + (size_t)(kvh * 32) * 8 * 512;
  const u16* Vbase = Vp + (size_t)(kvh * 32) * 8 * 512;

  auto loadK = [&](int kt, short8 (&kf)[4][2]) {
    const u16* kb = Kbase + (size_t)kt * 8 * 512 + lane * 8;
#pragma unroll
    for (int t = 0; t < 4; ++t) {
      kf[t][0] = *(const short8*)(kb + (t * 2 + 0) * 512);
      kf[t][1] = *(const short8*)(kb + (t * 2 + 1) * 512);
    }
  };

  auto body = [&](int kt, int ktmax, int baseq,
                  short8 (&qf)[2][2], floatx4 (&O)[2][4], float (&lsum)[2],
                  short8 (&kc)[4][2], short8 (&kn)[4][2]) {
    // V for CURRENT tile: issued first, consumed at the bottom
    short8 vb[2][4];
    {
      const u16* vbp = Vbase + (size_t)kt * 8 * 512 + lane * 8;
#pragma unroll
      for (int s = 0; s < 2; ++s)
#pragma unroll
        for (int t = 0; t < 4; ++t)
          vb[s][t] = *(const short8*)(vbp + (s * 4 + t) * 512);
    }

    // K for this wave's next tile (kt+2), clamped, branchless
    loadK(kt + 2 <= ktmax ? kt + 2 : ktmax, kn);

    // ---- S^T = K Q^T ----
    floatx4 ST[2][4];
#pragma unroll
    for (int i = 0; i < 2; ++i)
#pragma unroll
      for (int t = 0; t < 4; ++t) ST[i][t] = (floatx4){0.f, 0.f, 0.f, 0.f};
#pragma unroll
    for (int t = 0; t < 4; ++t)
#pragma unroll
      for (int i = 0; i < 2; ++i) {
        ST[i][t] = __builtin_amdgcn_mfma_f32_16x16x32_bf16(kc[t][0], qf[i][0], ST[i][t], 0, 0, 0);
        ST[i][t] = __builtin_amdgcn_mfma_f32_16x16x32_bf16(kc[t][1], qf[i][1], ST[i][t], 0, 0, 0);
      }

    // ---- causal mask (only the last tile of this q-block can clip) ----
    if (kt == ktmax) {
#pragma unroll
      for (int i = 0; i < 2; ++i) {
        int qrow = baseq + 16 * i + r;
#pragma unroll
        for (int t = 0; t < 4; ++t) {
          int key = kt * 64 + 16 * t + 4 * q;
#pragma unroll
          for (int g = 0; g < 4; ++g)
            if (key + g > qrow) ST[i][t][g] = -1e30f;
        }
      }
    }

    // ---- p = exp(scale*s); partial row-sums; packed P -> LDS ----
#pragma unroll
    for (int i = 0; i < 2; ++i)
#pragma unroll
      for (int t = 0; t < 4; ++t) {
        float p0 = __expf(0.125f * ST[i][t][0]);
        float p1 = __expf(0.125f * ST[i][t][1]);
        float p2 = __expf(0.125f * ST[i][t][2]);
        float p3 = __expf(0.125f * ST[i][t][3]);
        lsum[i] += (p0 + p1) + (p2 + p3);
        uint2 pk;
        pk.x = (unsigned)f2bf(p0) | ((unsigned)f2bf(p1) << 16);
        pk.y = (unsigned)f2bf(p2) | ((unsigned)f2bf(p3) << 16);
        *(uint2*)&Pl[w][16 * i + r][16 * t + 4 * q] = pk;   // ds_write_b64
      }

    // ---- O += P V ----
#pragma unroll
    for (int s = 0; s < 2; ++s)
#pragma unroll
      for (int i = 0; i < 2; ++i) {
        short8 pa = *(const short8*)&Pl[w][16 * i + r][32 * s + 8 * q];
#pragma unroll
        for (int t = 0; t < 4; ++t)
          O[i][t] = __builtin_amdgcn_mfma_f32_16x16x32_bf16(pa, vb[s][t], O[i][t], 0, 0, 0);
      }
  };

  auto runloop = [&](int start, int ktmax, int baseq,
                     short8 (&qf)[2][2], floatx4 (&O)[2][4], float (&lsum)[2]) {
    if (start > ktmax) return;
    short8 kA[4][2], kB[4][2];
    loadK(start, kA);
    for (int kt = start; kt <= ktmax; kt += 4) {
      body(kt, ktmax, baseq, qf, O, lsum, kA, kB);
      if (kt + 2 <= ktmax) body(kt + 2, ktmax, baseq, qf, O, lsum, kB, kA);
    }
  };

  // Wave w takes items [w::2] of the combined list [A-tiles..., B-tiles...]
  runloop(w, ktmaxA, baseqA, qfA, OA, lsumA);
  const int sB = (w + tA) & 1;   // parity continuation into the B-tiles
  runloop(sB, ktmaxB, baseqB, qfB, OB, lsumB);

  // ---- cross-wave combine ----
  if (w == 1) {
#pragma unroll
    for (int i = 0; i < 2; ++i) {
#pragma unroll
      for (int t = 0; t < 4; ++t)
#pragma unroll
        for (int g = 0; g < 4; ++g)
          OcA[(i * 4 + t) * 4 + g][lane] = OA[i][t][g];
      LcA[i][lane] = lsumA[i];
    }
  } else {
#pragma unroll
    for (int i = 0; i < 2; ++i) {
#pragma unroll
      for (int t = 0; t < 4; ++t)
#pragma unroll
        for (int g = 0; g < 4; ++g)
          OcB[(i * 4 + t) * 4 + g][lane] = OB[i][t][g];
      LcB[i][lane] = lsumB[i];
    }
  }
  __syncthreads();

  // finalize: normalize and store to PACKED Yb layout
  auto finalize = [&](int baseq, floatx4 (&O)[2][4], float (&lsum)[2]) {
#pragma unroll
    for (int i = 0; i < 2; ++i) {
      lsum[i] += __shfl_xor(lsum[i], 16);
      lsum[i] += __shfl_xor(lsum[i], 32);   // lane(q,r) holds sum for row r
    }
#pragma unroll
    for (int i = 0; i < 2; ++i) {
      float inv[4];
#pragma unroll
      for (int g = 0; g < 4; ++g)
        inv[g] = 1.f / __shfl(lsum[i], 4 * q + g);
#pragma unroll
      for (int g = 0; g < 4; ++g) {
        int rowi = baseq + 16 * i + 4 * q + g;
        size_t rbase = ((size_t)(rowi >> 4) * 64 + h * 2) * 512 +
                       (((r >> 3)) * 16 + (rowi & 15)) * 8 + (r & 7);
        Ybp[rbase]       = f2bf(O[i][0][g] * inv[g]);   // t=0
        Ybp[rbase + 256] = f2bf(O[i][1][g] * inv[g]);   // t=1
        Ybp[rbase + 512] = f2bf(O[i][2][g] * inv[g]);   // t=2
        Ybp[rbase + 768] = f2bf(O[i][3][g] * inv[g]);   // t=3
      }
    }
  };

  if (w == 0) {
#pragma unroll
    for (int i = 0; i < 2; ++i) {
#pragma unroll
      for (int t = 0; t < 4; ++t)
#pragma unroll
        for (int g = 0; g < 4; ++g)
          OA[i][t][g] += OcA[(i * 4 + t) * 4 + g][lane];
      lsumA[i] += LcA[i][lane];
    }
    finalize(baseqA, OA, lsumA);
  } else {
#pragma unroll
    for (int i = 0; i < 2; ++i) {
#pragma unroll
      for (int t = 0; t < 4; ++t)
#pragma unroll
        for (int g = 0; g < 4; ++g)
          OB[i][t][g] += OcB[(i * 4 + t) * 4 + g][lane];
      lsumB[i] += LcB[i][lane];
    }
    finalize(baseqB, OB, lsumB);
  }
}

// ---------------------------------------------------------------------------
extern "C" void kernel_launch(void* const* d_in, const int* in_sizes, int n_in,
                              void* d_out, int out_size, void* d_ws, size_t ws_size,
                              hipStream_t stream) {
  const float* x  = (const float*)d_in[0];
  const float* Wq = (const float*)d_in[1];
  const float* Wk = (const float*)d_in[2];
  const float* Wv = (const float*)d_in[3];
  const float* Wo = (const float*)d_in[4];
  const float* cs = (const float*)d_in[5];
  const float* sn = (const float*)d_in[6];

  u16* ws  = (u16*)d_ws;
  u16* xp  = ws + OFF_X;
  u16* Wqp = ws + OFF_WQ;
  u16* Wkp = ws + OFF_WK;
  u16* Wvp = ws + OFF_WV;
  u16* Wop = ws + OFF_WO;
  u16* Qp  = ws + OFF_QP;
  u16* Kp  = ws + OFF_KP;
  u16* Vp  = ws + OFF_VP;
  u16* Ybp = ws + OFF_YB;

  // fp32 -> bf16 + frag-pack (x + 4 weights)
  cvt_pack<<<dim3(6656), 256, 0, stream>>>(x, Wq, Wk, Wv, Wo, ws);

  // Fused QKV projection + RoPE, packed in, frag-packed out
  gemm_qkv<<<dim3(640), 256, 0, stream>>>(xp, Wqp, Wkp, Wvp, cs, sn, Qp, Kp, Vp);

  // Balanced pair-scheduled attention, writes packed Yb
  attn_mfma<<<dim3(32, 32), 128, 0, stream>>>(Qp, Kp, Vp, Ybp);

  // Output projection (packed A and B, fp32 straight to d_out)
  gemm_out<<<dim3(512), 256, 0, stream>>>(Ybp, Wop, (float*)d_out);
}